// Round 1
// baseline (13252.771 us; speedup 1.0000x reference)
//
#include <hip/hip_runtime.h>
#include <hip/hip_bf16.h>

#define DELTA 2.5749f
#define BN_EPS 1e-5f

// ---------------------------------------------------------------- CSR build
__global__ void k_degree(const int* __restrict__ dst, int* __restrict__ deg, int E) {
    int e = blockIdx.x * 256 + threadIdx.x;
    if (e < E) atomicAdd(&deg[dst[e]], 1);
}

#define SCAN_B 1024
__global__ void k_scan_block(const int* __restrict__ deg, int* __restrict__ excl,
                             int* __restrict__ bsums, int total) {
    __shared__ int s[SCAN_B];
    int t = threadIdx.x, i = blockIdx.x * SCAN_B + t;
    int v = (i < total) ? deg[i] : 0;
    s[t] = v; __syncthreads();
    for (int off = 1; off < SCAN_B; off <<= 1) {
        int x = (t >= off) ? s[t - off] : 0;
        __syncthreads();
        s[t] += x;
        __syncthreads();
    }
    if (i < total) excl[i] = s[t] - v;
    if (t == SCAN_B - 1) bsums[blockIdx.x] = s[t];
}

__global__ void k_scan_tops(int* __restrict__ bsums, int nb) {
    __shared__ int s[SCAN_B];
    int t = threadIdx.x;
    int v = (t < nb) ? bsums[t] : 0;
    s[t] = v; __syncthreads();
    for (int off = 1; off < SCAN_B; off <<= 1) {
        int x = (t >= off) ? s[t - off] : 0;
        __syncthreads();
        s[t] += x;
        __syncthreads();
    }
    if (t < nb) bsums[t] = s[t] - v;  // exclusive
}

__global__ void k_scan_add(int* __restrict__ excl, const int* __restrict__ bsums, int total) {
    int i = blockIdx.x * SCAN_B + threadIdx.x;
    if (i < total) excl[i] += bsums[blockIdx.x];
}

__global__ void k_fill(const int* __restrict__ src, const int* __restrict__ dst,
                       const int* __restrict__ rowptr, int* __restrict__ fill,
                       int* __restrict__ col, int E) {
    int e = blockIdx.x * 256 + threadIdx.x;
    if (e < E) {
        int d = dst[e];
        int pos = rowptr[d] + atomicAdd(&fill[d], 1);
        col[pos] = src[e];
    }
}

// ---------------------------------------------------------------- aggregation
// one wave per node; lane = feature. base layout per node: [sum(64)|max(64)|mean(64)|var(64)]
__global__ __launch_bounds__(256) void k_agg(const float* __restrict__ h,
                                             const int* __restrict__ rowptr,
                                             const int* __restrict__ col,
                                             float* __restrict__ base,
                                             float* __restrict__ cnt, int N) {
    int node = blockIdx.x * 4 + (threadIdx.x >> 6);
    int lane = threadIdx.x & 63;
    if (node >= N) return;
    int s0 = rowptr[node], s1 = rowptr[node + 1];
    float sum = 0.f, sq = 0.f, mx = -INFINITY;
    for (int e = s0; e < s1; ++e) {
        int s = __builtin_amdgcn_readfirstlane(col[e]);
        float v = h[(size_t)s * 64 + lane];
        sum += v; sq = fmaf(v, v, sq); mx = fmaxf(mx, v);
    }
    int deg = s1 - s0;
    float c = (float)(deg > 0 ? deg : 1);
    if (deg == 0) mx = 0.f;
    float mean = sum / c;
    float var = fmaxf(sq / c - mean * mean, 0.f);
    size_t b = (size_t)node * 256;
    base[b + lane] = sum;
    base[b + 64 + lane] = mx;
    base[b + 128 + lane] = mean;
    base[b + 192 + lane] = var;
    if (lane == 0) cnt[node] = c;
}

// ---------------------------------------------------------------- big GEMM: [N,256] x 3 matrices (256->64)
// out[n,d] = acc0 + (c/D)*acc1 + (D/c)*acc2 + mb[d] + hres[n,d]
__global__ __launch_bounds__(256) void k_gemm1(const float* __restrict__ base,
                                               const float* __restrict__ cnt,
                                               const float* __restrict__ mW,
                                               const float* __restrict__ mb,
                                               const float* __restrict__ hres,
                                               float* __restrict__ out, int N) {
    __shared__ float sBT[16][64];  // k-chunk x node (transposed)
    int t = threadIdx.x;
    int n0 = blockIdx.x * 64;
    int d = t & 63, nl = t >> 6;  // thread computes feat d for nodes nl*16 .. nl*16+15
    float acc0[16], acc1[16], acc2[16];
#pragma unroll
    for (int i = 0; i < 16; i++) { acc0[i] = 0.f; acc1[i] = 0.f; acc2[i] = 0.f; }
    const float* wrow = mW + (size_t)d * 768;
    int nn = t >> 2, c4 = (t & 3) * 4;  // staging assignment

    for (int kc = 0; kc < 256; kc += 16) {
        float4 w0[4], w1[4], w2[4];
#pragma unroll
        for (int j = 0; j < 4; j++) {
            w0[j] = *(const float4*)(wrow + kc + 4 * j);
            w1[j] = *(const float4*)(wrow + 256 + kc + 4 * j);
            w2[j] = *(const float4*)(wrow + 512 + kc + 4 * j);
        }
        float4 bv = make_float4(0.f, 0.f, 0.f, 0.f);
        if (n0 + nn < N) bv = *(const float4*)(base + (size_t)(n0 + nn) * 256 + kc + c4);
        __syncthreads();  // previous chunk's reads complete
        sBT[c4 + 0][nn] = bv.x; sBT[c4 + 1][nn] = bv.y;
        sBT[c4 + 2][nn] = bv.z; sBT[c4 + 3][nn] = bv.w;
        __syncthreads();
#pragma unroll
        for (int k = 0; k < 16; k++) {
            float wa = ((const float*)w0)[k];
            float wb = ((const float*)w1)[k];
            float wc = ((const float*)w2)[k];
            const float4* bp = (const float4*)(&sBT[k][nl * 16]);
#pragma unroll
            for (int q = 0; q < 4; q++) {
                float4 b4 = bp[q];
                float bs[4] = {b4.x, b4.y, b4.z, b4.w};
#pragma unroll
                for (int u = 0; u < 4; u++) {
                    int i = q * 4 + u;
                    acc0[i] = fmaf(bs[u], wa, acc0[i]);
                    acc1[i] = fmaf(bs[u], wb, acc1[i]);
                    acc2[i] = fmaf(bs[u], wc, acc2[i]);
                }
            }
        }
    }
    float bias = mb[d];
#pragma unroll
    for (int i = 0; i < 16; i++) {
        int n = n0 + nl * 16 + i;
        if (n < N) {
            float c = cnt[n];
            float v = acc0[i] + (c / DELTA) * acc1[i] + (DELTA / c) * acc2[i] + bias
                    + hres[(size_t)n * 64 + d];
            out[(size_t)n * 64 + d] = v;
        }
    }
}

// ---------------------------------------------------------------- 64x64 GEMM (encoder / nn1 / nn2)
template <bool RELU, bool BNSTAT>
__global__ __launch_bounds__(256) void k_gemm64(const float* __restrict__ in,
                                                const float* __restrict__ W,
                                                const float* __restrict__ bias,
                                                float* __restrict__ out,
                                                float* __restrict__ bnstat, int N) {
    __shared__ float sInT[64][64];  // k x node
    int t = threadIdx.x, d = t & 63, nl = t >> 6;
    int n0 = blockIdx.x * 64;
    float wr[64];
#pragma unroll
    for (int j = 0; j < 16; j++) {
        float4 w4 = *(const float4*)(W + (size_t)d * 64 + 4 * j);
        wr[4 * j + 0] = w4.x; wr[4 * j + 1] = w4.y;
        wr[4 * j + 2] = w4.z; wr[4 * j + 3] = w4.w;
    }
#pragma unroll
    for (int ch = 0; ch < 4; ch++) {
        int lin = t + ch * 256;
        int r = lin >> 4, cc = (lin & 15) * 4;
        float4 v = make_float4(0.f, 0.f, 0.f, 0.f);
        if (n0 + r < N) v = *(const float4*)(in + (size_t)(n0 + r) * 64 + cc);
        sInT[cc + 0][r] = v.x; sInT[cc + 1][r] = v.y;
        sInT[cc + 2][r] = v.z; sInT[cc + 3][r] = v.w;
    }
    __syncthreads();
    float acc[16];
#pragma unroll
    for (int i = 0; i < 16; i++) acc[i] = 0.f;
#pragma unroll
    for (int k = 0; k < 64; k++) {
        const float4* bp = (const float4*)(&sInT[k][nl * 16]);
        float w = wr[k];
#pragma unroll
        for (int q = 0; q < 4; q++) {
            float4 b4 = bp[q];
            acc[q * 4 + 0] = fmaf(b4.x, w, acc[q * 4 + 0]);
            acc[q * 4 + 1] = fmaf(b4.y, w, acc[q * 4 + 1]);
            acc[q * 4 + 2] = fmaf(b4.z, w, acc[q * 4 + 2]);
            acc[q * 4 + 3] = fmaf(b4.w, w, acc[q * 4 + 3]);
        }
    }
    float b = bias[d];
    float s1 = 0.f, s2 = 0.f;
#pragma unroll
    for (int i = 0; i < 16; i++) {
        int n = n0 + nl * 16 + i;
        if (n < N) {
            float v = acc[i] + b;
            if (RELU) v = fmaxf(v, 0.f);
            out[(size_t)n * 64 + d] = v;
            if (BNSTAT) { s1 += v; s2 = fmaf(v, v, s2); }
        }
    }
    if (BNSTAT) {
        __syncthreads();  // done reading sInT
        float* red = (float*)sInT;
        red[nl * 128 + d] = s1;
        red[nl * 128 + 64 + d] = s2;
        __syncthreads();
        if (t < 128) {
            float tot = red[t] + red[128 + t] + red[256 + t] + red[384 + t];
            atomicAdd(&bnstat[t], tot);
        }
    }
}

// ---------------------------------------------------------------- batchnorm apply
__global__ void k_bn(const float* __restrict__ in, const float* __restrict__ stat,
                     const float* __restrict__ gamma, const float* __restrict__ beta,
                     float* __restrict__ outh, int total, float invN) {
    int idx = blockIdx.x * 256 + threadIdx.x;
    if (idx >= total) return;
    int d = idx & 63;
    float mu = stat[d] * invN;
    float var = stat[64 + d] * invN - mu * mu;
    float sc = rsqrtf(var + BN_EPS) * gamma[d];
    outh[idx] = (in[idx] - mu) * sc + beta[d];
}

// ---------------------------------------------------------------- pool (batch is sorted)
__global__ void k_pool(const float* __restrict__ h, const int* __restrict__ batch,
                       float* __restrict__ g, int N) {
    int d = threadIdx.x & 63, r = threadIdx.x >> 6;
    int nbase = blockIdx.x * 32;
    float acc = 0.f;
    int gcur = -1;
    for (int i = 0; i < 8; i++) {
        int n = nbase + i * 4 + r;
        if (n < N) {
            int gb = batch[n];
            if (gb != gcur) {
                if (gcur >= 0) atomicAdd(&g[gcur * 64 + d], acc);
                acc = 0.f; gcur = gb;
            }
            acc += h[(size_t)n * 64 + d];
        }
    }
    if (gcur >= 0) atomicAdd(&g[gcur * 64 + d], acc);
}

// ---------------------------------------------------------------- head: relu(g@fc1)+fc2
__global__ void k_head(const float* __restrict__ g, const float* __restrict__ fc1W,
                       const float* __restrict__ fc1b, const float* __restrict__ fc2W,
                       const float* __restrict__ fc2b, float* __restrict__ out) {
    __shared__ float sg[64], sg1[64];
    int gi = blockIdx.x, t = threadIdx.x;
    sg[t] = g[gi * 64 + t];
    __syncthreads();
    float a = fc1b[t];
    for (int k = 0; k < 64; k++) a = fmaf(sg[k], fc1W[t * 64 + k], a);
    sg1[t] = fmaxf(a, 0.f);
    __syncthreads();
    if (t < 16) {
        float o = fc2b[t];
        for (int k = 0; k < 64; k++) o = fmaf(sg1[k], fc2W[t * 64 + k], o);
        out[gi * 16 + t] = o;
    }
}

// ---------------------------------------------------------------- launcher
extern "C" void kernel_launch(void* const* d_in, const int* in_sizes, int n_in,
                              void* d_out, int out_size, void* d_ws, size_t ws_size,
                              hipStream_t stream) {
    const float* x       = (const float*)d_in[0];
    const int*   eidx    = (const int*)d_in[1];
    const int*   batch   = (const int*)d_in[2];
    const float* encW    = (const float*)d_in[3];
    const float* encb    = (const float*)d_in[4];
    const float* nnW1    = (const float*)d_in[5];
    const float* nnb1    = (const float*)d_in[6];
    const float* nnW2    = (const float*)d_in[7];
    const float* nnb2    = (const float*)d_in[8];
    const float* mlpW    = (const float*)d_in[9];
    const float* mlpb    = (const float*)d_in[10];
    const float* bnG     = (const float*)d_in[11];
    const float* bnB     = (const float*)d_in[12];
    const float* fc1W    = (const float*)d_in[13];
    const float* fc1b    = (const float*)d_in[14];
    const float* fc2W    = (const float*)d_in[15];
    const float* fc2b    = (const float*)d_in[16];
    float* out = (float*)d_out;

    const int N = in_sizes[0] / 64;
    const int E = in_sizes[1] / 2;
    const int G = 512;
    const int* src = eidx;
    const int* dst = eidx + E;

    // workspace layout
    char* ws = (char*)d_ws;
    size_t off = 0;
    auto alloc = [&](size_t bytes) { size_t r = off; off = (off + bytes + 255) & ~(size_t)255; return r; };
    int*   deg     = (int*)(ws + alloc((size_t)(N + 1) * 4));
    int*   rowptr  = (int*)(ws + alloc((size_t)(N + 1) * 4));
    int*   bsums   = (int*)(ws + alloc(1024 * 4));
    int*   fill    = (int*)(ws + alloc((size_t)N * 4));
    int*   col     = (int*)(ws + alloc((size_t)E * 4));
    float* cnt     = (float*)(ws + alloc((size_t)N * 4));
    float* h0      = (float*)(ws + alloc((size_t)N * 64 * 4));
    float* baseb   = (float*)(ws + alloc((size_t)N * 256 * 4));
    float* hA      = (float*)(ws + alloc((size_t)N * 64 * 4));
    float* hB      = (float*)(ws + alloc((size_t)N * 64 * 4));
    float* bnstats = (float*)(ws + alloc(5 * 128 * 4));
    float* gpool   = (float*)(ws + alloc((size_t)G * 64 * 4));

    hipMemsetAsync(deg, 0, (size_t)(N + 1) * 4, stream);
    hipMemsetAsync(fill, 0, (size_t)N * 4, stream);
    hipMemsetAsync(bnstats, 0, 5 * 128 * 4, stream);
    hipMemsetAsync(gpool, 0, (size_t)G * 64 * 4, stream);

    int egrid = (E + 255) / 256;
    int total = N + 1;
    int nscan = (total + SCAN_B - 1) / SCAN_B;
    int ngrid64 = (N + 63) / 64;

    k_degree<<<egrid, 256, 0, stream>>>(dst, deg, E);
    k_scan_block<<<nscan, SCAN_B, 0, stream>>>(deg, rowptr, bsums, total);
    k_scan_tops<<<1, SCAN_B, 0, stream>>>(bsums, nscan);
    k_scan_add<<<nscan, SCAN_B, 0, stream>>>(rowptr, bsums, total);
    k_fill<<<egrid, 256, 0, stream>>>(src, dst, rowptr, fill, col, E);

    // encoder: h0 = x @ encW.T + encb
    k_gemm64<false, false><<<ngrid64, 256, 0, stream>>>(x, encW, encb, h0, nullptr, N);

    for (int i = 0; i < 5; i++) {
        k_agg<<<(N + 3) / 4, 256, 0, stream>>>(h0, rowptr, col, baseb, cnt, N);
        k_gemm1<<<ngrid64, 256, 0, stream>>>(baseb, cnt, mlpW + (size_t)i * 64 * 768,
                                             mlpb + i * 64, h0, hA, N);
        k_gemm64<true, false><<<ngrid64, 256, 0, stream>>>(hA, nnW1 + (size_t)i * 4096,
                                                           nnb1 + i * 64, hB, nullptr, N);
        k_gemm64<true, true><<<ngrid64, 256, 0, stream>>>(hB, nnW2 + (size_t)i * 4096,
                                                          nnb2 + i * 64, hA, bnstats + i * 128, N);
        k_bn<<<(N * 64 + 255) / 256, 256, 0, stream>>>(hA, bnstats + i * 128, bnG + i * 64,
                                                       bnB + i * 64, h0, N * 64, 1.f / (float)N);
    }

    k_pool<<<(N + 31) / 32, 256, 0, stream>>>(h0, batch, gpool, N);
    k_head<<<G, 64, 0, stream>>>(gpool, fc1W, fc1b, fc2W, fc2b, out);
}

// Round 2
// 2438.786 us; speedup vs baseline: 5.4342x; 5.4342x over previous
//
#include <hip/hip_runtime.h>
#include <hip/hip_bf16.h>

#define DELTA 2.5749f
#define BN_EPS 1e-5f

// ---------------------------------------------------------------- CSR build
__global__ void k_degree(const int* __restrict__ dst, int* __restrict__ deg, int E) {
    int e = blockIdx.x * 256 + threadIdx.x;
    if (e < E) atomicAdd(&deg[dst[e]], 1);
}

#define SCAN_B 1024
__global__ void k_scan_block(const int* __restrict__ deg, int* __restrict__ excl,
                             int* __restrict__ bsums, int total) {
    __shared__ int s[SCAN_B];
    int t = threadIdx.x, i = blockIdx.x * SCAN_B + t;
    int v = (i < total) ? deg[i] : 0;
    s[t] = v; __syncthreads();
    for (int off = 1; off < SCAN_B; off <<= 1) {
        int x = (t >= off) ? s[t - off] : 0;
        __syncthreads();
        s[t] += x;
        __syncthreads();
    }
    if (i < total) excl[i] = s[t] - v;
    if (t == SCAN_B - 1) bsums[blockIdx.x] = s[t];
}

__global__ void k_scan_tops(int* __restrict__ bsums, int nb) {
    __shared__ int s[SCAN_B];
    int t = threadIdx.x;
    int v = (t < nb) ? bsums[t] : 0;
    s[t] = v; __syncthreads();
    for (int off = 1; off < SCAN_B; off <<= 1) {
        int x = (t >= off) ? s[t - off] : 0;
        __syncthreads();
        s[t] += x;
        __syncthreads();
    }
    if (t < nb) bsums[t] = s[t] - v;  // exclusive
}

__global__ void k_scan_add(int* __restrict__ excl, const int* __restrict__ bsums, int total) {
    int i = blockIdx.x * SCAN_B + threadIdx.x;
    if (i < total) excl[i] += bsums[blockIdx.x];
}

__global__ void k_fill(const int* __restrict__ src, const int* __restrict__ dst,
                       const int* __restrict__ rowptr, int* __restrict__ fill,
                       int* __restrict__ col, int E) {
    int e = blockIdx.x * 256 + threadIdx.x;
    if (e < E) {
        int d = dst[e];
        int pos = rowptr[d] + atomicAdd(&fill[d], 1);
        col[pos] = src[e];
    }
}

// ---------------------------------------------------------------- aggregation
// one wave per node; lane = feature. base layout per node: [sum(64)|max(64)|mean(64)|var(64)]
__global__ __launch_bounds__(256) void k_agg(const float* __restrict__ h,
                                             const int* __restrict__ rowptr,
                                             const int* __restrict__ col,
                                             float* __restrict__ base,
                                             float* __restrict__ cnt, int N) {
    int node = blockIdx.x * 4 + (threadIdx.x >> 6);
    int lane = threadIdx.x & 63;
    if (node >= N) return;
    int s0 = rowptr[node], s1 = rowptr[node + 1];
    float sum = 0.f, sq = 0.f, mx = -INFINITY;
    for (int e = s0; e < s1; ++e) {
        int s = __builtin_amdgcn_readfirstlane(col[e]);
        float v = h[(size_t)s * 64 + lane];
        sum += v; sq = fmaf(v, v, sq); mx = fmaxf(mx, v);
    }
    int deg = s1 - s0;
    float c = (float)(deg > 0 ? deg : 1);
    if (deg == 0) mx = 0.f;
    float mean = sum / c;
    float var = fmaxf(sq / c - mean * mean, 0.f);
    size_t b = (size_t)node * 256;
    base[b + lane] = sum;
    base[b + 64 + lane] = mx;
    base[b + 128 + lane] = mean;
    base[b + 192 + lane] = var;
    if (lane == 0) cnt[node] = c;
}

// ---------------------------------------------------------------- big GEMM: [N,256] x 3 matrices (256->64)
// out[n,d] = acc0 + (c/D)*acc1 + (D/c)*acc2 + mb[d] + hres[n,d]
__global__ __launch_bounds__(256) void k_gemm1(const float* __restrict__ base,
                                               const float* __restrict__ cnt,
                                               const float* __restrict__ mW,
                                               const float* __restrict__ mb,
                                               const float* __restrict__ hres,
                                               float* __restrict__ out, int N) {
    __shared__ float sBT[16][64];  // k-chunk x node (transposed)
    int t = threadIdx.x;
    int n0 = blockIdx.x * 64;
    int d = t & 63, nl = t >> 6;  // thread computes feat d for nodes nl*16 .. nl*16+15
    float acc0[16], acc1[16], acc2[16];
#pragma unroll
    for (int i = 0; i < 16; i++) { acc0[i] = 0.f; acc1[i] = 0.f; acc2[i] = 0.f; }
    const float* wrow = mW + (size_t)d * 768;
    int nn = t >> 2, c4 = (t & 3) * 4;  // staging assignment

    for (int kc = 0; kc < 256; kc += 16) {
        float4 w0[4], w1[4], w2[4];
#pragma unroll
        for (int j = 0; j < 4; j++) {
            w0[j] = *(const float4*)(wrow + kc + 4 * j);
            w1[j] = *(const float4*)(wrow + 256 + kc + 4 * j);
            w2[j] = *(const float4*)(wrow + 512 + kc + 4 * j);
        }
        float4 bv = make_float4(0.f, 0.f, 0.f, 0.f);
        if (n0 + nn < N) bv = *(const float4*)(base + (size_t)(n0 + nn) * 256 + kc + c4);
        __syncthreads();  // previous chunk's reads complete
        sBT[c4 + 0][nn] = bv.x; sBT[c4 + 1][nn] = bv.y;
        sBT[c4 + 2][nn] = bv.z; sBT[c4 + 3][nn] = bv.w;
        __syncthreads();
#pragma unroll
        for (int k = 0; k < 16; k++) {
            float wa = ((const float*)w0)[k];
            float wb = ((const float*)w1)[k];
            float wc = ((const float*)w2)[k];
            const float4* bp = (const float4*)(&sBT[k][nl * 16]);
#pragma unroll
            for (int q = 0; q < 4; q++) {
                float4 b4 = bp[q];
                float bs[4] = {b4.x, b4.y, b4.z, b4.w};
#pragma unroll
                for (int u = 0; u < 4; u++) {
                    int i = q * 4 + u;
                    acc0[i] = fmaf(bs[u], wa, acc0[i]);
                    acc1[i] = fmaf(bs[u], wb, acc1[i]);
                    acc2[i] = fmaf(bs[u], wc, acc2[i]);
                }
            }
        }
    }
    float bias = mb[d];
#pragma unroll
    for (int i = 0; i < 16; i++) {
        int n = n0 + nl * 16 + i;
        if (n < N) {
            float c = cnt[n];
            float v = acc0[i] + (c / DELTA) * acc1[i] + (DELTA / c) * acc2[i] + bias
                    + hres[(size_t)n * 64 + d];
            out[(size_t)n * 64 + d] = v;
        }
    }
}

// ---------------------------------------------------------------- 64x64 GEMM (encoder / nn1 / nn2)
// 4x4 micro-tile per thread, NO per-thread arrays (spill-proof).
#define FMA16(ACC0, ACC1, ACC2, ACC3, A, W)                                \
    do {                                                                   \
        ACC0.x = fmaf(A.x, W.x, ACC0.x); ACC0.y = fmaf(A.x, W.y, ACC0.y);  \
        ACC0.z = fmaf(A.x, W.z, ACC0.z); ACC0.w = fmaf(A.x, W.w, ACC0.w);  \
        ACC1.x = fmaf(A.y, W.x, ACC1.x); ACC1.y = fmaf(A.y, W.y, ACC1.y);  \
        ACC1.z = fmaf(A.y, W.z, ACC1.z); ACC1.w = fmaf(A.y, W.w, ACC1.w);  \
        ACC2.x = fmaf(A.z, W.x, ACC2.x); ACC2.y = fmaf(A.z, W.y, ACC2.y);  \
        ACC2.z = fmaf(A.z, W.z, ACC2.z); ACC2.w = fmaf(A.z, W.w, ACC2.w);  \
        ACC3.x = fmaf(A.w, W.x, ACC3.x); ACC3.y = fmaf(A.w, W.y, ACC3.y);  \
        ACC3.z = fmaf(A.w, W.z, ACC3.z); ACC3.w = fmaf(A.w, W.w, ACC3.w);  \
    } while (0)

template <bool RELU, bool BNSTAT>
__global__ __launch_bounds__(256) void k_gemm64(const float* __restrict__ in,
                                                const float* __restrict__ W,
                                                const float* __restrict__ bias,
                                                float* __restrict__ out,
                                                float* __restrict__ bnstat, int N) {
    __shared__ float sInT[64][64];  // [k][node]
    __shared__ float sWT[64][64];   // [k][feat]
    int t = threadIdx.x;
    int tx = t & 15, ty = t >> 4;   // feat group / node group
    int n0 = blockIdx.x * 64;
    int c4 = tx * 4;
    // stage both tiles transposed (4 passes of 16 rows x 64 cols)
#pragma unroll
    for (int ch = 0; ch < 4; ch++) {
        int row = ch * 16 + ty;
        float4 v = make_float4(0.f, 0.f, 0.f, 0.f);
        if (n0 + row < N) v = *(const float4*)(in + (size_t)(n0 + row) * 64 + c4);
        sInT[c4 + 0][row] = v.x; sInT[c4 + 1][row] = v.y;
        sInT[c4 + 2][row] = v.z; sInT[c4 + 3][row] = v.w;
        float4 w = *(const float4*)(W + (size_t)row * 64 + c4);
        sWT[c4 + 0][row] = w.x; sWT[c4 + 1][row] = w.y;
        sWT[c4 + 2][row] = w.z; sWT[c4 + 3][row] = w.w;
    }
    __syncthreads();
    float4 acc0 = make_float4(0.f, 0.f, 0.f, 0.f);
    float4 acc1 = acc0, acc2 = acc0, acc3 = acc0;
#pragma unroll 8
    for (int k = 0; k < 64; k++) {
        float4 a = *(const float4*)(&sInT[k][ty * 4]);
        float4 w = *(const float4*)(&sWT[k][tx * 4]);
        FMA16(acc0, acc1, acc2, acc3, a, w);
    }
    float4 b4 = *(const float4*)(bias + tx * 4);
    float4 s1 = make_float4(0.f, 0.f, 0.f, 0.f);
    float4 s2 = s1;
#pragma unroll
    for (int i = 0; i < 4; i++) {
        int n = n0 + ty * 4 + i;
        if (n < N) {
            float4 v = (i == 0) ? acc0 : (i == 1) ? acc1 : (i == 2) ? acc2 : acc3;
            v.x += b4.x; v.y += b4.y; v.z += b4.z; v.w += b4.w;
            if (RELU) {
                v.x = fmaxf(v.x, 0.f); v.y = fmaxf(v.y, 0.f);
                v.z = fmaxf(v.z, 0.f); v.w = fmaxf(v.w, 0.f);
            }
            *(float4*)(out + (size_t)n * 64 + tx * 4) = v;
            if (BNSTAT) {
                s1.x += v.x; s1.y += v.y; s1.z += v.z; s1.w += v.w;
                s2.x = fmaf(v.x, v.x, s2.x); s2.y = fmaf(v.y, v.y, s2.y);
                s2.z = fmaf(v.z, v.z, s2.z); s2.w = fmaf(v.w, v.w, s2.w);
            }
        }
    }
    if (BNSTAT) {
        __syncthreads();  // done with sInT, reuse for reduction
        float* red = &sInT[0][0];  // 4096 floats; [0:1024)=s1, [1024:2048)=s2
        *(float4*)(red + ty * 64 + tx * 4) = s1;
        *(float4*)(red + 1024 + ty * 64 + tx * 4) = s2;
        __syncthreads();
        if (t < 128) {
            int d = t & 63;
            int base = (t >> 6) * 1024;
            float tot = 0.f;
#pragma unroll
            for (int r2 = 0; r2 < 16; r2++) tot += red[base + r2 * 64 + d];
            atomicAdd(&bnstat[(t >> 6) * 64 + d], tot);
        }
    }
}

// ---------------------------------------------------------------- batchnorm apply
__global__ void k_bn(const float* __restrict__ in, const float* __restrict__ stat,
                     const float* __restrict__ gamma, const float* __restrict__ beta,
                     float* __restrict__ outh, int total, float invN) {
    int idx = blockIdx.x * 256 + threadIdx.x;
    if (idx >= total) return;
    int d = idx & 63;
    float mu = stat[d] * invN;
    float var = stat[64 + d] * invN - mu * mu;
    float sc = rsqrtf(var + BN_EPS) * gamma[d];
    outh[idx] = (in[idx] - mu) * sc + beta[d];
}

// ---------------------------------------------------------------- pool (batch is sorted)
__global__ void k_pool(const float* __restrict__ h, const int* __restrict__ batch,
                       float* __restrict__ g, int N) {
    int d = threadIdx.x & 63, r = threadIdx.x >> 6;
    int nbase = blockIdx.x * 32;
    float acc = 0.f;
    int gcur = -1;
    for (int i = 0; i < 8; i++) {
        int n = nbase + i * 4 + r;
        if (n < N) {
            int gb = batch[n];
            if (gb != gcur) {
                if (gcur >= 0) atomicAdd(&g[gcur * 64 + d], acc);
                acc = 0.f; gcur = gb;
            }
            acc += h[(size_t)n * 64 + d];
        }
    }
    if (gcur >= 0) atomicAdd(&g[gcur * 64 + d], acc);
}

// ---------------------------------------------------------------- head: relu(g@fc1)+fc2
__global__ void k_head(const float* __restrict__ g, const float* __restrict__ fc1W,
                       const float* __restrict__ fc1b, const float* __restrict__ fc2W,
                       const float* __restrict__ fc2b, float* __restrict__ out) {
    __shared__ float sg[64], sg1[64];
    int gi = blockIdx.x, t = threadIdx.x;
    sg[t] = g[gi * 64 + t];
    __syncthreads();
    float a = fc1b[t];
    for (int k = 0; k < 64; k++) a = fmaf(sg[k], fc1W[t * 64 + k], a);
    sg1[t] = fmaxf(a, 0.f);
    __syncthreads();
    if (t < 16) {
        float o = fc2b[t];
        for (int k = 0; k < 64; k++) o = fmaf(sg1[k], fc2W[t * 64 + k], o);
        out[gi * 16 + t] = o;
    }
}

// ---------------------------------------------------------------- launcher
extern "C" void kernel_launch(void* const* d_in, const int* in_sizes, int n_in,
                              void* d_out, int out_size, void* d_ws, size_t ws_size,
                              hipStream_t stream) {
    const float* x       = (const float*)d_in[0];
    const int*   eidx    = (const int*)d_in[1];
    const int*   batch   = (const int*)d_in[2];
    const float* encW    = (const float*)d_in[3];
    const float* encb    = (const float*)d_in[4];
    const float* nnW1    = (const float*)d_in[5];
    const float* nnb1    = (const float*)d_in[6];
    const float* nnW2    = (const float*)d_in[7];
    const float* nnb2    = (const float*)d_in[8];
    const float* mlpW    = (const float*)d_in[9];
    const float* mlpb    = (const float*)d_in[10];
    const float* bnG     = (const float*)d_in[11];
    const float* bnB     = (const float*)d_in[12];
    const float* fc1W    = (const float*)d_in[13];
    const float* fc1b    = (const float*)d_in[14];
    const float* fc2W    = (const float*)d_in[15];
    const float* fc2b    = (const float*)d_in[16];
    float* out = (float*)d_out;

    const int N = in_sizes[0] / 64;
    const int E = in_sizes[1] / 2;
    const int G = 512;
    const int* src = eidx;
    const int* dst = eidx + E;

    // workspace layout
    char* ws = (char*)d_ws;
    size_t off = 0;
    auto alloc = [&](size_t bytes) { size_t r = off; off = (off + bytes + 255) & ~(size_t)255; return r; };
    int*   deg     = (int*)(ws + alloc((size_t)(N + 1) * 4));
    int*   rowptr  = (int*)(ws + alloc((size_t)(N + 1) * 4));
    int*   bsums   = (int*)(ws + alloc(1024 * 4));
    int*   fill    = (int*)(ws + alloc((size_t)N * 4));
    int*   col     = (int*)(ws + alloc((size_t)E * 4));
    float* cnt     = (float*)(ws + alloc((size_t)N * 4));
    float* h0      = (float*)(ws + alloc((size_t)N * 64 * 4));
    float* baseb   = (float*)(ws + alloc((size_t)N * 256 * 4));
    float* hA      = (float*)(ws + alloc((size_t)N * 64 * 4));
    float* hB      = (float*)(ws + alloc((size_t)N * 64 * 4));
    float* bnstats = (float*)(ws + alloc(5 * 128 * 4));
    float* gpool   = (float*)(ws + alloc((size_t)G * 64 * 4));

    hipMemsetAsync(deg, 0, (size_t)(N + 1) * 4, stream);
    hipMemsetAsync(fill, 0, (size_t)N * 4, stream);
    hipMemsetAsync(bnstats, 0, 5 * 128 * 4, stream);
    hipMemsetAsync(gpool, 0, (size_t)G * 64 * 4, stream);

    int egrid = (E + 255) / 256;
    int total = N + 1;
    int nscan = (total + SCAN_B - 1) / SCAN_B;
    int ngrid64 = (N + 63) / 64;

    k_degree<<<egrid, 256, 0, stream>>>(dst, deg, E);
    k_scan_block<<<nscan, SCAN_B, 0, stream>>>(deg, rowptr, bsums, total);
    k_scan_tops<<<1, SCAN_B, 0, stream>>>(bsums, nscan);
    k_scan_add<<<nscan, SCAN_B, 0, stream>>>(rowptr, bsums, total);
    k_fill<<<egrid, 256, 0, stream>>>(src, dst, rowptr, fill, col, E);

    // encoder: h0 = x @ encW.T + encb
    k_gemm64<false, false><<<ngrid64, 256, 0, stream>>>(x, encW, encb, h0, nullptr, N);

    for (int i = 0; i < 5; i++) {
        k_agg<<<(N + 3) / 4, 256, 0, stream>>>(h0, rowptr, col, baseb, cnt, N);
        k_gemm1<<<ngrid64, 256, 0, stream>>>(baseb, cnt, mlpW + (size_t)i * 64 * 768,
                                             mlpb + i * 64, h0, hA, N);
        k_gemm64<true, false><<<ngrid64, 256, 0, stream>>>(hA, nnW1 + (size_t)i * 4096,
                                                           nnb1 + i * 64, hB, nullptr, N);
        k_gemm64<true, true><<<ngrid64, 256, 0, stream>>>(hB, nnW2 + (size_t)i * 4096,
                                                          nnb2 + i * 64, hA, bnstats + i * 128, N);
        k_bn<<<(N * 64 + 255) / 256, 256, 0, stream>>>(hA, bnstats + i * 128, bnG + i * 64,
                                                       bnB + i * 64, h0, N * 64, 1.f / (float)N);
    }

    k_pool<<<(N + 31) / 32, 256, 0, stream>>>(h0, batch, gpool, N);
    k_head<<<G, 64, 0, stream>>>(gpool, fc1W, fc1b, fc2W, fc2b, out);
}

// Round 3
// 2090.811 us; speedup vs baseline: 6.3386x; 1.1664x over previous
//
#include <hip/hip_runtime.h>
#include <hip/hip_bf16.h>

#define DELTA 2.5749f
#define BN_EPS 1e-5f

// ---------------------------------------------------------------- CSR build
__global__ void k_degree(const int* __restrict__ dst, int* __restrict__ deg, int E) {
    int e = blockIdx.x * 256 + threadIdx.x;
    if (e < E) atomicAdd(&deg[dst[e]], 1);
}

#define SCAN_B 1024
__global__ void k_scan_block(const int* __restrict__ deg, int* __restrict__ excl,
                             int* __restrict__ bsums, int total) {
    __shared__ int s[SCAN_B];
    int t = threadIdx.x, i = blockIdx.x * SCAN_B + t;
    int v = (i < total) ? deg[i] : 0;
    s[t] = v; __syncthreads();
    for (int off = 1; off < SCAN_B; off <<= 1) {
        int x = (t >= off) ? s[t - off] : 0;
        __syncthreads();
        s[t] += x;
        __syncthreads();
    }
    if (i < total) excl[i] = s[t] - v;
    if (t == SCAN_B - 1) bsums[blockIdx.x] = s[t];
}

__global__ void k_scan_tops(int* __restrict__ bsums, int nb) {
    __shared__ int s[SCAN_B];
    int t = threadIdx.x;
    int v = (t < nb) ? bsums[t] : 0;
    s[t] = v; __syncthreads();
    for (int off = 1; off < SCAN_B; off <<= 1) {
        int x = (t >= off) ? s[t - off] : 0;
        __syncthreads();
        s[t] += x;
        __syncthreads();
    }
    if (t < nb) bsums[t] = s[t] - v;  // exclusive
}

__global__ void k_scan_add(int* __restrict__ excl, const int* __restrict__ bsums, int total) {
    int i = blockIdx.x * SCAN_B + threadIdx.x;
    if (i < total) excl[i] += bsums[blockIdx.x];
}

__global__ void k_fill(const int* __restrict__ src, const int* __restrict__ dst,
                       const int* __restrict__ rowptr, int* __restrict__ fill,
                       int* __restrict__ col, int E) {
    int e = blockIdx.x * 256 + threadIdx.x;
    if (e < E) {
        int d = dst[e];
        int pos = rowptr[d] + atomicAdd(&fill[d], 1);
        col[pos] = src[e];
    }
}

// ---------------------------------------------------------------- aggregation
// one wave per node; 16 lanes per edge (float4), 4 edges in flight.
// base layout per node: [sum(64)|max(64)|mean(64)|var(64)]
__global__ __launch_bounds__(256) void k_agg(const float* __restrict__ h,
                                             const int* __restrict__ rowptr,
                                             const int* __restrict__ col,
                                             float* __restrict__ base,
                                             float* __restrict__ cnt, int N) {
    int node = blockIdx.x * 4 + (threadIdx.x >> 6);
    int lane = threadIdx.x & 63;
    if (node >= N) return;
    int slot = lane >> 4;        // which of 4 concurrent edges
    int fo = (lane & 15) * 4;    // feature offset
    int s0 = rowptr[node], s1 = rowptr[node + 1];
    int deg = s1 - s0;
    float4 sum = make_float4(0.f, 0.f, 0.f, 0.f);
    float4 sq = sum;
    float4 mx = make_float4(-INFINITY, -INFINITY, -INFINITY, -INFINITY);
    for (int e = s0 + slot; e < s1; e += 4) {
        int s = __ldg(col + e);
        float4 v = *(const float4*)(h + (size_t)s * 64 + fo);
        sum.x += v.x; sum.y += v.y; sum.z += v.z; sum.w += v.w;
        sq.x = fmaf(v.x, v.x, sq.x); sq.y = fmaf(v.y, v.y, sq.y);
        sq.z = fmaf(v.z, v.z, sq.z); sq.w = fmaf(v.w, v.w, sq.w);
        mx.x = fmaxf(mx.x, v.x); mx.y = fmaxf(mx.y, v.y);
        mx.z = fmaxf(mx.z, v.z); mx.w = fmaxf(mx.w, v.w);
    }
    // butterfly reduce across the 4 slots (lane xor 16, 32)
#pragma unroll
    for (int m = 16; m <= 32; m <<= 1) {
        sum.x += __shfl_xor(sum.x, m); sum.y += __shfl_xor(sum.y, m);
        sum.z += __shfl_xor(sum.z, m); sum.w += __shfl_xor(sum.w, m);
        sq.x += __shfl_xor(sq.x, m); sq.y += __shfl_xor(sq.y, m);
        sq.z += __shfl_xor(sq.z, m); sq.w += __shfl_xor(sq.w, m);
        mx.x = fmaxf(mx.x, __shfl_xor(mx.x, m)); mx.y = fmaxf(mx.y, __shfl_xor(mx.y, m));
        mx.z = fmaxf(mx.z, __shfl_xor(mx.z, m)); mx.w = fmaxf(mx.w, __shfl_xor(mx.w, m));
    }
    float c = (float)(deg > 0 ? deg : 1);
    float ic = 1.f / c;
    float4 mean = make_float4(sum.x * ic, sum.y * ic, sum.z * ic, sum.w * ic);
    float4 var = make_float4(fmaxf(fmaf(-mean.x, mean.x, sq.x * ic), 0.f),
                             fmaxf(fmaf(-mean.y, mean.y, sq.y * ic), 0.f),
                             fmaxf(fmaf(-mean.z, mean.z, sq.z * ic), 0.f),
                             fmaxf(fmaf(-mean.w, mean.w, sq.w * ic), 0.f));
    if (deg == 0) mx = make_float4(0.f, 0.f, 0.f, 0.f);
    // slot j writes segment j: 0=sum 1=max 2=mean 3=var -> 1KB contiguous store
    float4 wv = (slot == 0) ? sum : (slot == 1) ? mx : (slot == 2) ? mean : var;
    *(float4*)(base + (size_t)node * 256 + slot * 64 + fo) = wv;
    if (lane == 0) cnt[node] = c;
}

// ---------------------------------------------------------------- big GEMM: [N,256] x 3 matrices (256->64)
// Full 64x256 base tile staged transposed in LDS once; k-loop is barrier-free.
// out[n,d] = acc0 + (c/D)*acc1 + (D/c)*acc2 + mb[d] + hres[n,d]
__global__ __launch_bounds__(256) void k_gemm1(const float* __restrict__ base,
                                               const float* __restrict__ cnt,
                                               const float* __restrict__ mW,
                                               const float* __restrict__ mb,
                                               const float* __restrict__ hres,
                                               float* __restrict__ out, int N) {
    __shared__ float sBT[256][64];  // [k][node], 64 KB
    int t = threadIdx.x;
    int n0 = blockIdx.x * 64;
    int d = t & 63, nl = t >> 6;  // thread: feat d, nodes nl*16 .. +15

    // stage whole tile: thread t loads node nn, k = kc0+16j .. +3
    {
        int nn = t >> 2, kc0 = (t & 3) * 4;
        const float* brow = base + (size_t)(n0 + nn) * 256;
        bool valid = (n0 + nn) < N;
#pragma unroll
        for (int j = 0; j < 16; j++) {
            float4 bv = make_float4(0.f, 0.f, 0.f, 0.f);
            if (valid) bv = *(const float4*)(brow + kc0 + 16 * j);
            int k = kc0 + 16 * j;
            sBT[k + 0][nn] = bv.x; sBT[k + 1][nn] = bv.y;
            sBT[k + 2][nn] = bv.z; sBT[k + 3][nn] = bv.w;
        }
    }
    __syncthreads();

    float acc0[16], acc1[16], acc2[16];
#pragma unroll
    for (int i = 0; i < 16; i++) { acc0[i] = 0.f; acc1[i] = 0.f; acc2[i] = 0.f; }
    const float* wrow = mW + (size_t)d * 768;

#pragma unroll 1
    for (int kc = 0; kc < 256; kc += 16) {
        float4 w0[4], w1[4], w2[4];
#pragma unroll
        for (int j = 0; j < 4; j++) {
            w0[j] = *(const float4*)(wrow + kc + 4 * j);
            w1[j] = *(const float4*)(wrow + 256 + kc + 4 * j);
            w2[j] = *(const float4*)(wrow + 512 + kc + 4 * j);
        }
#pragma unroll
        for (int k = 0; k < 16; k++) {
            float wa = ((const float*)w0)[k];
            float wb = ((const float*)w1)[k];
            float wc = ((const float*)w2)[k];
            const float4* bp = (const float4*)(&sBT[kc + k][nl * 16]);
#pragma unroll
            for (int q = 0; q < 4; q++) {
                float4 b4 = bp[q];
                float bs[4] = {b4.x, b4.y, b4.z, b4.w};
#pragma unroll
                for (int u = 0; u < 4; u++) {
                    int i = q * 4 + u;
                    acc0[i] = fmaf(bs[u], wa, acc0[i]);
                    acc1[i] = fmaf(bs[u], wb, acc1[i]);
                    acc2[i] = fmaf(bs[u], wc, acc2[i]);
                }
            }
        }
    }
    float bias = mb[d];
#pragma unroll
    for (int i = 0; i < 16; i++) {
        int n = n0 + nl * 16 + i;
        if (n < N) {
            float c = cnt[n];
            float v = acc0[i] + (c / DELTA) * acc1[i] + (DELTA / c) * acc2[i] + bias
                    + hres[(size_t)n * 64 + d];
            out[(size_t)n * 64 + d] = v;
        }
    }
}

// ---------------------------------------------------------------- 64x64 GEMM (encoder / nn1 / nn2)
// 4x4 micro-tile per thread, NO per-thread arrays (spill-proof).
#define FMA16(ACC0, ACC1, ACC2, ACC3, A, W)                                \
    do {                                                                   \
        ACC0.x = fmaf(A.x, W.x, ACC0.x); ACC0.y = fmaf(A.x, W.y, ACC0.y);  \
        ACC0.z = fmaf(A.x, W.z, ACC0.z); ACC0.w = fmaf(A.x, W.w, ACC0.w);  \
        ACC1.x = fmaf(A.y, W.x, ACC1.x); ACC1.y = fmaf(A.y, W.y, ACC1.y);  \
        ACC1.z = fmaf(A.y, W.z, ACC1.z); ACC1.w = fmaf(A.y, W.w, ACC1.w);  \
        ACC2.x = fmaf(A.z, W.x, ACC2.x); ACC2.y = fmaf(A.z, W.y, ACC2.y);  \
        ACC2.z = fmaf(A.z, W.z, ACC2.z); ACC2.w = fmaf(A.z, W.w, ACC2.w);  \
        ACC3.x = fmaf(A.w, W.x, ACC3.x); ACC3.y = fmaf(A.w, W.y, ACC3.y);  \
        ACC3.z = fmaf(A.w, W.z, ACC3.z); ACC3.w = fmaf(A.w, W.w, ACC3.w);  \
    } while (0)

template <bool RELU, bool BNSTAT>
__global__ __launch_bounds__(256) void k_gemm64(const float* __restrict__ in,
                                                const float* __restrict__ W,
                                                const float* __restrict__ bias,
                                                float* __restrict__ out,
                                                float* __restrict__ bnstat, int N) {
    __shared__ float sInT[64][64];  // [k][node]
    __shared__ float sWT[64][64];   // [k][feat]
    int t = threadIdx.x;
    int tx = t & 15, ty = t >> 4;   // feat group / node group
    int n0 = blockIdx.x * 64;
    int c4 = tx * 4;
#pragma unroll
    for (int ch = 0; ch < 4; ch++) {
        int row = ch * 16 + ty;
        float4 v = make_float4(0.f, 0.f, 0.f, 0.f);
        if (n0 + row < N) v = *(const float4*)(in + (size_t)(n0 + row) * 64 + c4);
        sInT[c4 + 0][row] = v.x; sInT[c4 + 1][row] = v.y;
        sInT[c4 + 2][row] = v.z; sInT[c4 + 3][row] = v.w;
        float4 w = *(const float4*)(W + (size_t)row * 64 + c4);
        sWT[c4 + 0][row] = w.x; sWT[c4 + 1][row] = w.y;
        sWT[c4 + 2][row] = w.z; sWT[c4 + 3][row] = w.w;
    }
    __syncthreads();
    float4 acc0 = make_float4(0.f, 0.f, 0.f, 0.f);
    float4 acc1 = acc0, acc2 = acc0, acc3 = acc0;
#pragma unroll 8
    for (int k = 0; k < 64; k++) {
        float4 a = *(const float4*)(&sInT[k][ty * 4]);
        float4 w = *(const float4*)(&sWT[k][tx * 4]);
        FMA16(acc0, acc1, acc2, acc3, a, w);
    }
    float4 b4 = *(const float4*)(bias + tx * 4);
    float4 s1 = make_float4(0.f, 0.f, 0.f, 0.f);
    float4 s2 = s1;
#pragma unroll
    for (int i = 0; i < 4; i++) {
        int n = n0 + ty * 4 + i;
        if (n < N) {
            float4 v = (i == 0) ? acc0 : (i == 1) ? acc1 : (i == 2) ? acc2 : acc3;
            v.x += b4.x; v.y += b4.y; v.z += b4.z; v.w += b4.w;
            if (RELU) {
                v.x = fmaxf(v.x, 0.f); v.y = fmaxf(v.y, 0.f);
                v.z = fmaxf(v.z, 0.f); v.w = fmaxf(v.w, 0.f);
            }
            *(float4*)(out + (size_t)n * 64 + tx * 4) = v;
            if (BNSTAT) {
                s1.x += v.x; s1.y += v.y; s1.z += v.z; s1.w += v.w;
                s2.x = fmaf(v.x, v.x, s2.x); s2.y = fmaf(v.y, v.y, s2.y);
                s2.z = fmaf(v.z, v.z, s2.z); s2.w = fmaf(v.w, v.w, s2.w);
            }
        }
    }
    if (BNSTAT) {
        __syncthreads();  // done with sInT, reuse for reduction
        float* red = &sInT[0][0];  // [0:1024)=s1, [1024:2048)=s2
        *(float4*)(red + ty * 64 + tx * 4) = s1;
        *(float4*)(red + 1024 + ty * 64 + tx * 4) = s2;
        __syncthreads();
        if (t < 128) {
            int d = t & 63;
            int base = (t >> 6) * 1024;
            float tot = 0.f;
#pragma unroll
            for (int r2 = 0; r2 < 16; r2++) tot += red[base + r2 * 64 + d];
            atomicAdd(&bnstat[(t >> 6) * 64 + d], tot);
        }
    }
}

// ---------------------------------------------------------------- batchnorm apply
__global__ void k_bn(const float* __restrict__ in, const float* __restrict__ stat,
                     const float* __restrict__ gamma, const float* __restrict__ beta,
                     float* __restrict__ outh, int total, float invN) {
    int idx = blockIdx.x * 256 + threadIdx.x;
    if (idx >= total) return;
    int d = idx & 63;
    float mu = stat[d] * invN;
    float var = stat[64 + d] * invN - mu * mu;
    float sc = rsqrtf(var + BN_EPS) * gamma[d];
    outh[idx] = (in[idx] - mu) * sc + beta[d];
}

// ---------------------------------------------------------------- pool (batch is sorted)
__global__ void k_pool(const float* __restrict__ h, const int* __restrict__ batch,
                       float* __restrict__ g, int N) {
    int d = threadIdx.x & 63, r = threadIdx.x >> 6;
    int nbase = blockIdx.x * 32;
    float acc = 0.f;
    int gcur = -1;
    for (int i = 0; i < 8; i++) {
        int n = nbase + i * 4 + r;
        if (n < N) {
            int gb = batch[n];
            if (gb != gcur) {
                if (gcur >= 0) atomicAdd(&g[gcur * 64 + d], acc);
                acc = 0.f; gcur = gb;
            }
            acc += h[(size_t)n * 64 + d];
        }
    }
    if (gcur >= 0) atomicAdd(&g[gcur * 64 + d], acc);
}

// ---------------------------------------------------------------- head: relu(g@fc1)+fc2
__global__ void k_head(const float* __restrict__ g, const float* __restrict__ fc1W,
                       const float* __restrict__ fc1b, const float* __restrict__ fc2W,
                       const float* __restrict__ fc2b, float* __restrict__ out) {
    __shared__ float sg[64], sg1[64];
    int gi = blockIdx.x, t = threadIdx.x;
    sg[t] = g[gi * 64 + t];
    __syncthreads();
    float a = fc1b[t];
    for (int k = 0; k < 64; k++) a = fmaf(sg[k], fc1W[t * 64 + k], a);
    sg1[t] = fmaxf(a, 0.f);
    __syncthreads();
    if (t < 16) {
        float o = fc2b[t];
        for (int k = 0; k < 64; k++) o = fmaf(sg1[k], fc2W[t * 64 + k], o);
        out[gi * 16 + t] = o;
    }
}

// ---------------------------------------------------------------- launcher
extern "C" void kernel_launch(void* const* d_in, const int* in_sizes, int n_in,
                              void* d_out, int out_size, void* d_ws, size_t ws_size,
                              hipStream_t stream) {
    const float* x       = (const float*)d_in[0];
    const int*   eidx    = (const int*)d_in[1];
    const int*   batch   = (const int*)d_in[2];
    const float* encW    = (const float*)d_in[3];
    const float* encb    = (const float*)d_in[4];
    const float* nnW1    = (const float*)d_in[5];
    const float* nnb1    = (const float*)d_in[6];
    const float* nnW2    = (const float*)d_in[7];
    const float* nnb2    = (const float*)d_in[8];
    const float* mlpW    = (const float*)d_in[9];
    const float* mlpb    = (const float*)d_in[10];
    const float* bnG     = (const float*)d_in[11];
    const float* bnB     = (const float*)d_in[12];
    const float* fc1W    = (const float*)d_in[13];
    const float* fc1b    = (const float*)d_in[14];
    const float* fc2W    = (const float*)d_in[15];
    const float* fc2b    = (const float*)d_in[16];
    float* out = (float*)d_out;

    const int N = in_sizes[0] / 64;
    const int E = in_sizes[1] / 2;
    const int G = 512;
    const int* src = eidx;
    const int* dst = eidx + E;

    // workspace layout
    char* ws = (char*)d_ws;
    size_t off = 0;
    auto alloc = [&](size_t bytes) { size_t r = off; off = (off + bytes + 255) & ~(size_t)255; return r; };
    int*   deg     = (int*)(ws + alloc((size_t)(N + 1) * 4));
    int*   rowptr  = (int*)(ws + alloc((size_t)(N + 1) * 4));
    int*   bsums   = (int*)(ws + alloc(1024 * 4));
    int*   fill    = (int*)(ws + alloc((size_t)N * 4));
    int*   col     = (int*)(ws + alloc((size_t)E * 4));
    float* cnt     = (float*)(ws + alloc((size_t)N * 4));
    float* h0      = (float*)(ws + alloc((size_t)N * 64 * 4));
    float* baseb   = (float*)(ws + alloc((size_t)N * 256 * 4));
    float* hA      = (float*)(ws + alloc((size_t)N * 64 * 4));
    float* hB      = (float*)(ws + alloc((size_t)N * 64 * 4));
    float* bnstats = (float*)(ws + alloc(5 * 128 * 4));
    float* gpool   = (float*)(ws + alloc((size_t)G * 64 * 4));

    hipMemsetAsync(deg, 0, (size_t)(N + 1) * 4, stream);
    hipMemsetAsync(fill, 0, (size_t)N * 4, stream);
    hipMemsetAsync(bnstats, 0, 5 * 128 * 4, stream);
    hipMemsetAsync(gpool, 0, (size_t)G * 64 * 4, stream);

    int egrid = (E + 255) / 256;
    int total = N + 1;
    int nscan = (total + SCAN_B - 1) / SCAN_B;
    int ngrid64 = (N + 63) / 64;

    k_degree<<<egrid, 256, 0, stream>>>(dst, deg, E);
    k_scan_block<<<nscan, SCAN_B, 0, stream>>>(deg, rowptr, bsums, total);
    k_scan_tops<<<1, SCAN_B, 0, stream>>>(bsums, nscan);
    k_scan_add<<<nscan, SCAN_B, 0, stream>>>(rowptr, bsums, total);
    k_fill<<<egrid, 256, 0, stream>>>(src, dst, rowptr, fill, col, E);

    // encoder: h0 = x @ encW.T + encb
    k_gemm64<false, false><<<ngrid64, 256, 0, stream>>>(x, encW, encb, h0, nullptr, N);

    for (int i = 0; i < 5; i++) {
        k_agg<<<(N + 3) / 4, 256, 0, stream>>>(h0, rowptr, col, baseb, cnt, N);
        k_gemm1<<<ngrid64, 256, 0, stream>>>(baseb, cnt, mlpW + (size_t)i * 64 * 768,
                                             mlpb + i * 64, h0, hA, N);
        k_gemm64<true, false><<<ngrid64, 256, 0, stream>>>(hA, nnW1 + (size_t)i * 4096,
                                                           nnb1 + i * 64, hB, nullptr, N);
        k_gemm64<true, true><<<ngrid64, 256, 0, stream>>>(hB, nnW2 + (size_t)i * 4096,
                                                          nnb2 + i * 64, hA, bnstats + i * 128, N);
        k_bn<<<(N * 64 + 255) / 256, 256, 0, stream>>>(hA, bnstats + i * 128, bnG + i * 64,
                                                       bnB + i * 64, h0, N * 64, 1.f / (float)N);
    }

    k_pool<<<(N + 31) / 32, 256, 0, stream>>>(h0, batch, gpool, N);
    k_head<<<G, 64, 0, stream>>>(gpool, fc1W, fc1b, fc2W, fc2b, out);
}

// Round 5
// 1644.726 us; speedup vs baseline: 8.0577x; 1.2712x over previous
//
#include <hip/hip_runtime.h>
#include <hip/hip_bf16.h>

#define DELTA 2.5749f
#define BN_EPS 1e-5f

typedef __attribute__((ext_vector_type(8))) short bf16x8;
typedef __attribute__((ext_vector_type(4))) float f32x4;

__device__ inline unsigned short f2bf(float f) {
    union { float f; unsigned int u; } v; v.f = f;
    unsigned int r = v.u + 0x7fff + ((v.u >> 16) & 1);  // RNE
    return (unsigned short)(r >> 16);
}
__device__ inline float bf2f(unsigned short h) {
    union { unsigned int u; float f; } v; v.u = ((unsigned int)h) << 16;
    return v.f;
}

// ---------------------------------------------------------------- CSR build
__global__ void k_degree(const int* __restrict__ dst, int* __restrict__ deg, int E) {
    int e = blockIdx.x * 256 + threadIdx.x;
    if (e < E) atomicAdd(&deg[dst[e]], 1);
}

#define SCAN_B 1024
__global__ void k_scan_block(const int* __restrict__ deg, int* __restrict__ excl,
                             int* __restrict__ bsums, int total) {
    __shared__ int s[SCAN_B];
    int t = threadIdx.x, i = blockIdx.x * SCAN_B + t;
    int v = (i < total) ? deg[i] : 0;
    s[t] = v; __syncthreads();
    for (int off = 1; off < SCAN_B; off <<= 1) {
        int x = (t >= off) ? s[t - off] : 0;
        __syncthreads();
        s[t] += x;
        __syncthreads();
    }
    if (i < total) excl[i] = s[t] - v;
    if (t == SCAN_B - 1) bsums[blockIdx.x] = s[t];
}

__global__ void k_scan_tops(int* __restrict__ bsums, int nb) {
    __shared__ int s[SCAN_B];
    int t = threadIdx.x;
    int v = (t < nb) ? bsums[t] : 0;
    s[t] = v; __syncthreads();
    for (int off = 1; off < SCAN_B; off <<= 1) {
        int x = (t >= off) ? s[t - off] : 0;
        __syncthreads();
        s[t] += x;
        __syncthreads();
    }
    if (t < nb) bsums[t] = s[t] - v;  // exclusive
}

__global__ void k_scan_add(int* __restrict__ excl, const int* __restrict__ bsums, int total) {
    int i = blockIdx.x * SCAN_B + threadIdx.x;
    if (i < total) excl[i] += bsums[blockIdx.x];
}

__global__ void k_fill(const int* __restrict__ src, const int* __restrict__ dst,
                       const int* __restrict__ rowptr, int* __restrict__ fill,
                       int* __restrict__ col, int E) {
    int e = blockIdx.x * 256 + threadIdx.x;
    if (e < E) {
        int d = dst[e];
        int pos = rowptr[d] + atomicAdd(&fill[d], 1);
        col[pos] = src[e];
    }
}

// ---------------------------------------------------------------- weight cast f32 -> bf16 hi/lo planes
__global__ void k_castw(const float* __restrict__ w, unsigned short* __restrict__ oh,
                        unsigned short* __restrict__ ol, int n4) {
    int i = blockIdx.x * 256 + threadIdx.x;
    if (i < n4) {
        float4 v = ((const float4*)w)[i];
        ushort4 rh, rl;
        rh.x = f2bf(v.x); rl.x = f2bf(v.x - bf2f(rh.x));
        rh.y = f2bf(v.y); rl.y = f2bf(v.y - bf2f(rh.y));
        rh.z = f2bf(v.z); rl.z = f2bf(v.z - bf2f(rh.z));
        rh.w = f2bf(v.w); rl.w = f2bf(v.w - bf2f(rh.w));
        ((ushort4*)oh)[i] = rh;
        ((ushort4*)ol)[i] = rl;
    }
}

// ---------------------------------------------------------------- aggregation
// one wave per node; 16 lanes per edge (float4), unroll 2 -> 8 gathers in flight.
// base (bf16 hi/lo planes) layout per node: [sum(64)|max(64)|mean(64)|var(64)]
__global__ __launch_bounds__(256) void k_agg(const float* __restrict__ h,
                                             const int* __restrict__ rowptr,
                                             const int* __restrict__ col,
                                             unsigned short* __restrict__ baseH,
                                             unsigned short* __restrict__ baseL,
                                             float* __restrict__ cnt, int N) {
    int node = blockIdx.x * 4 + (threadIdx.x >> 6);
    int lane = threadIdx.x & 63;
    if (node >= N) return;
    int slot = lane >> 4;        // which of 4 concurrent edges
    int fo = (lane & 15) * 4;    // feature offset
    int s0 = rowptr[node], s1 = rowptr[node + 1];
    int deg = s1 - s0;
    float4 sum = make_float4(0.f, 0.f, 0.f, 0.f);
    float4 sq = sum;
    float4 mx = make_float4(-INFINITY, -INFINITY, -INFINITY, -INFINITY);
    int e = s0 + slot;
    for (; e + 4 < s1; e += 8) {
        int sA = col[e], sB = col[e + 4];
        float4 v1 = *(const float4*)(h + (size_t)sA * 64 + fo);
        float4 v2 = *(const float4*)(h + (size_t)sB * 64 + fo);
        sum.x += v1.x; sum.y += v1.y; sum.z += v1.z; sum.w += v1.w;
        sq.x = fmaf(v1.x, v1.x, sq.x); sq.y = fmaf(v1.y, v1.y, sq.y);
        sq.z = fmaf(v1.z, v1.z, sq.z); sq.w = fmaf(v1.w, v1.w, sq.w);
        mx.x = fmaxf(mx.x, v1.x); mx.y = fmaxf(mx.y, v1.y);
        mx.z = fmaxf(mx.z, v1.z); mx.w = fmaxf(mx.w, v1.w);
        sum.x += v2.x; sum.y += v2.y; sum.z += v2.z; sum.w += v2.w;
        sq.x = fmaf(v2.x, v2.x, sq.x); sq.y = fmaf(v2.y, v2.y, sq.y);
        sq.z = fmaf(v2.z, v2.z, sq.z); sq.w = fmaf(v2.w, v2.w, sq.w);
        mx.x = fmaxf(mx.x, v2.x); mx.y = fmaxf(mx.y, v2.y);
        mx.z = fmaxf(mx.z, v2.z); mx.w = fmaxf(mx.w, v2.w);
    }
    if (e < s1) {
        int s = col[e];
        float4 v = *(const float4*)(h + (size_t)s * 64 + fo);
        sum.x += v.x; sum.y += v.y; sum.z += v.z; sum.w += v.w;
        sq.x = fmaf(v.x, v.x, sq.x); sq.y = fmaf(v.y, v.y, sq.y);
        sq.z = fmaf(v.z, v.z, sq.z); sq.w = fmaf(v.w, v.w, sq.w);
        mx.x = fmaxf(mx.x, v.x); mx.y = fmaxf(mx.y, v.y);
        mx.z = fmaxf(mx.z, v.z); mx.w = fmaxf(mx.w, v.w);
    }
    // butterfly reduce across the 4 slots (lane xor 16, 32)
#pragma unroll
    for (int m = 16; m <= 32; m <<= 1) {
        sum.x += __shfl_xor(sum.x, m); sum.y += __shfl_xor(sum.y, m);
        sum.z += __shfl_xor(sum.z, m); sum.w += __shfl_xor(sum.w, m);
        sq.x += __shfl_xor(sq.x, m); sq.y += __shfl_xor(sq.y, m);
        sq.z += __shfl_xor(sq.z, m); sq.w += __shfl_xor(sq.w, m);
        mx.x = fmaxf(mx.x, __shfl_xor(mx.x, m)); mx.y = fmaxf(mx.y, __shfl_xor(mx.y, m));
        mx.z = fmaxf(mx.z, __shfl_xor(mx.z, m)); mx.w = fmaxf(mx.w, __shfl_xor(mx.w, m));
    }
    float c = (float)(deg > 0 ? deg : 1);
    float ic = 1.f / c;
    float4 mean = make_float4(sum.x * ic, sum.y * ic, sum.z * ic, sum.w * ic);
    float4 var = make_float4(fmaxf(fmaf(-mean.x, mean.x, sq.x * ic), 0.f),
                             fmaxf(fmaf(-mean.y, mean.y, sq.y * ic), 0.f),
                             fmaxf(fmaf(-mean.z, mean.z, sq.z * ic), 0.f),
                             fmaxf(fmaf(-mean.w, mean.w, sq.w * ic), 0.f));
    if (deg == 0) mx = make_float4(0.f, 0.f, 0.f, 0.f);
    // slot j writes segment j: 0=sum 1=max 2=mean 3=var (bf16 hi/lo)
    float4 wv = (slot == 0) ? sum : (slot == 1) ? mx : (slot == 2) ? mean : var;
    ushort4 oh, ol;
    oh.x = f2bf(wv.x); ol.x = f2bf(wv.x - bf2f(oh.x));
    oh.y = f2bf(wv.y); ol.y = f2bf(wv.y - bf2f(oh.y));
    oh.z = f2bf(wv.z); ol.z = f2bf(wv.z - bf2f(oh.z));
    oh.w = f2bf(wv.w); ol.w = f2bf(wv.w - bf2f(oh.w));
    size_t boff = (size_t)node * 256 + slot * 64 + fo;
    *(ushort4*)(baseH + boff) = oh;
    *(ushort4*)(baseL + boff) = ol;
    if (lane == 0) cnt[node] = c;
}

// ---------------------------------------------------------------- big GEMM via MFMA bf16 split-precision
// base[N,256] (bf16 hi+lo) x mW^T rows (bf16 hi+lo): 3 output matrices fused.
// wave = TWO 16-node m-tiles sharing B fragments; acc = AhiBhi + AloBhi + AhiBlo.
__global__ __launch_bounds__(256) void k_gemm1(const unsigned short* __restrict__ baseH,
                                               const unsigned short* __restrict__ baseL,
                                               const float* __restrict__ cnt,
                                               const unsigned short* __restrict__ mWH,
                                               const unsigned short* __restrict__ mWL,
                                               const float* __restrict__ mb,
                                               const float* __restrict__ hres,
                                               float* __restrict__ out, int N) {
    int t = threadIdx.x;
    int wave = t >> 6, lane = t & 63;
    int r16 = lane & 15, quad = lane >> 4;
    int m0 = blockIdx.x * 128 + wave * 32;   // first m-tile; second is m0+16
    // A: lane holds base[m+r16][quad*8 + j + ks]  (16B contiguous)
    size_t aoff0 = (size_t)(m0 + r16) * 256 + quad * 8;
    size_t aoff1 = (size_t)(m0 + 16 + r16) * 256 + quad * 8;
    // B: lane holds W row (out-feat = nt*16+r16), k-contiguous
    const unsigned short* bH = mWH + (size_t)r16 * 768 + quad * 8;
    const unsigned short* bL = mWL + (size_t)r16 * 768 + quad * 8;
    f32x4 acc0[12], acc1[12];
#pragma unroll
    for (int i = 0; i < 12; i++) {
        acc0[i] = (f32x4){0.f, 0.f, 0.f, 0.f};
        acc1[i] = (f32x4){0.f, 0.f, 0.f, 0.f};
    }
#pragma unroll 1
    for (int ks = 0; ks < 256; ks += 32) {
        bf16x8 aH0 = *(const bf16x8*)(baseH + aoff0 + ks);
        bf16x8 aL0 = *(const bf16x8*)(baseL + aoff0 + ks);
        bf16x8 aH1 = *(const bf16x8*)(baseH + aoff1 + ks);
        bf16x8 aL1 = *(const bf16x8*)(baseL + aoff1 + ks);
#pragma unroll
        for (int mat = 0; mat < 3; mat++) {
#pragma unroll
            for (int nt = 0; nt < 4; nt++) {
                size_t woff = (size_t)nt * (16 * 768) + mat * 256 + ks;
                bf16x8 wH = *(const bf16x8*)(bH + woff);
                bf16x8 wL = *(const bf16x8*)(bL + woff);
                int id = mat * 4 + nt;
                acc0[id] = __builtin_amdgcn_mfma_f32_16x16x32_bf16(aH0, wH, acc0[id], 0, 0, 0);
                acc1[id] = __builtin_amdgcn_mfma_f32_16x16x32_bf16(aH1, wH, acc1[id], 0, 0, 0);
                acc0[id] = __builtin_amdgcn_mfma_f32_16x16x32_bf16(aL0, wH, acc0[id], 0, 0, 0);
                acc1[id] = __builtin_amdgcn_mfma_f32_16x16x32_bf16(aL1, wH, acc1[id], 0, 0, 0);
                acc0[id] = __builtin_amdgcn_mfma_f32_16x16x32_bf16(aH0, wL, acc0[id], 0, 0, 0);
                acc1[id] = __builtin_amdgcn_mfma_f32_16x16x32_bf16(aH1, wL, acc1[id], 0, 0, 0);
            }
        }
    }
    // epilogue: D row = quad*4+reg (node within tile), col = r16 (feat within n-tile)
#pragma unroll
    for (int mt = 0; mt < 2; mt++) {
#pragma unroll
        for (int i = 0; i < 4; i++) {
            int node = m0 + mt * 16 + quad * 4 + i;
            if (node < N) {
                float c = cnt[node];
                float amp = c / DELTA, att = DELTA / c;
#pragma unroll
                for (int nt = 0; nt < 4; nt++) {
                    int feat = nt * 16 + r16;
                    f32x4* a = mt ? acc1 : acc0;
                    float v = a[nt][i] + amp * a[4 + nt][i] + att * a[8 + nt][i]
                            + mb[feat] + hres[(size_t)node * 64 + feat];
                    out[(size_t)node * 64 + feat] = v;
                }
            }
        }
    }
}

// ---------------------------------------------------------------- 64x64 GEMM (encoder / nn1 / nn2)
#define FMA16(ACC0, ACC1, ACC2, ACC3, A, W)                                \
    do {                                                                   \
        ACC0.x = fmaf(A.x, W.x, ACC0.x); ACC0.y = fmaf(A.x, W.y, ACC0.y);  \
        ACC0.z = fmaf(A.x, W.z, ACC0.z); ACC0.w = fmaf(A.x, W.w, ACC0.w);  \
        ACC1.x = fmaf(A.y, W.x, ACC1.x); ACC1.y = fmaf(A.y, W.y, ACC1.y);  \
        ACC1.z = fmaf(A.y, W.z, ACC1.z); ACC1.w = fmaf(A.y, W.w, ACC1.w);  \
        ACC2.x = fmaf(A.z, W.x, ACC2.x); ACC2.y = fmaf(A.z, W.y, ACC2.y);  \
        ACC2.z = fmaf(A.z, W.z, ACC2.z); ACC2.w = fmaf(A.z, W.w, ACC2.w);  \
        ACC3.x = fmaf(A.w, W.x, ACC3.x); ACC3.y = fmaf(A.w, W.y, ACC3.y);  \
        ACC3.z = fmaf(A.w, W.z, ACC3.z); ACC3.w = fmaf(A.w, W.w, ACC3.w);  \
    } while (0)

template <bool RELU, bool BNSTAT>
__global__ __launch_bounds__(256) void k_gemm64(const float* __restrict__ in,
                                                const float* __restrict__ W,
                                                const float* __restrict__ bias,
                                                float* __restrict__ out,
                                                float* __restrict__ bnstat, int N) {
    __shared__ float sInT[64][64];  // [k][node]
    __shared__ float sWT[64][64];   // [k][feat]
    int t = threadIdx.x;
    int tx = t & 15, ty = t >> 4;
    int n0 = blockIdx.x * 64;
    int c4 = tx * 4;
#pragma unroll
    for (int ch = 0; ch < 4; ch++) {
        int row = ch * 16 + ty;
        float4 v = make_float4(0.f, 0.f, 0.f, 0.f);
        if (n0 + row < N) v = *(const float4*)(in + (size_t)(n0 + row) * 64 + c4);
        sInT[c4 + 0][row] = v.x; sInT[c4 + 1][row] = v.y;
        sInT[c4 + 2][row] = v.z; sInT[c4 + 3][row] = v.w;
        float4 w = *(const float4*)(W + (size_t)row * 64 + c4);
        sWT[c4 + 0][row] = w.x; sWT[c4 + 1][row] = w.y;
        sWT[c4 + 2][row] = w.z; sWT[c4 + 3][row] = w.w;
    }
    __syncthreads();
    float4 acc0 = make_float4(0.f, 0.f, 0.f, 0.f);
    float4 acc1 = acc0, acc2 = acc0, acc3 = acc0;
#pragma unroll 8
    for (int k = 0; k < 64; k++) {
        float4 a = *(const float4*)(&sInT[k][ty * 4]);
        float4 w = *(const float4*)(&sWT[k][tx * 4]);
        FMA16(acc0, acc1, acc2, acc3, a, w);
    }
    float4 b4 = *(const float4*)(bias + tx * 4);
    float4 s1 = make_float4(0.f, 0.f, 0.f, 0.f);
    float4 s2 = s1;
#pragma unroll
    for (int i = 0; i < 4; i++) {
        int n = n0 + ty * 4 + i;
        if (n < N) {
            float4 v = (i == 0) ? acc0 : (i == 1) ? acc1 : (i == 2) ? acc2 : acc3;
            v.x += b4.x; v.y += b4.y; v.z += b4.z; v.w += b4.w;
            if (RELU) {
                v.x = fmaxf(v.x, 0.f); v.y = fmaxf(v.y, 0.f);
                v.z = fmaxf(v.z, 0.f); v.w = fmaxf(v.w, 0.f);
            }
            *(float4*)(out + (size_t)n * 64 + tx * 4) = v;
            if (BNSTAT) {
                s1.x += v.x; s1.y += v.y; s1.z += v.z; s1.w += v.w;
                s2.x = fmaf(v.x, v.x, s2.x); s2.y = fmaf(v.y, v.y, s2.y);
                s2.z = fmaf(v.z, v.z, s2.z); s2.w = fmaf(v.w, v.w, s2.w);
            }
        }
    }
    if (BNSTAT) {
        __syncthreads();
        float* red = &sInT[0][0];
        *(float4*)(red + ty * 64 + tx * 4) = s1;
        *(float4*)(red + 1024 + ty * 64 + tx * 4) = s2;
        __syncthreads();
        if (t < 128) {
            int d = t & 63;
            int base = (t >> 6) * 1024;
            float tot = 0.f;
#pragma unroll
            for (int r2 = 0; r2 < 16; r2++) tot += red[base + r2 * 64 + d];
            atomicAdd(&bnstat[(t >> 6) * 64 + d], tot);
        }
    }
}

// ---------------------------------------------------------------- batchnorm apply
__global__ void k_bn(const float* __restrict__ in, const float* __restrict__ stat,
                     const float* __restrict__ gamma, const float* __restrict__ beta,
                     float* __restrict__ outh, int total, float invN) {
    int idx = blockIdx.x * 256 + threadIdx.x;
    if (idx >= total) return;
    int d = idx & 63;
    float mu = stat[d] * invN;
    float var = stat[64 + d] * invN - mu * mu;
    float sc = rsqrtf(var + BN_EPS) * gamma[d];
    outh[idx] = (in[idx] - mu) * sc + beta[d];
}

// ---------------------------------------------------------------- pool (batch is sorted)
__global__ void k_pool(const float* __restrict__ h, const int* __restrict__ batch,
                       float* __restrict__ g, int N) {
    int d = threadIdx.x & 63, r = threadIdx.x >> 6;
    int nbase = blockIdx.x * 32;
    float acc = 0.f;
    int gcur = -1;
    for (int i = 0; i < 8; i++) {
        int n = nbase + i * 4 + r;
        if (n < N) {
            int gb = batch[n];
            if (gb != gcur) {
                if (gcur >= 0) atomicAdd(&g[gcur * 64 + d], acc);
                acc = 0.f; gcur = gb;
            }
            acc += h[(size_t)n * 64 + d];
        }
    }
    if (gcur >= 0) atomicAdd(&g[gcur * 64 + d], acc);
}

// ---------------------------------------------------------------- head: relu(g@fc1)+fc2
__global__ void k_head(const float* __restrict__ g, const float* __restrict__ fc1W,
                       const float* __restrict__ fc1b, const float* __restrict__ fc2W,
                       const float* __restrict__ fc2b, float* __restrict__ out) {
    __shared__ float sg[64], sg1[64];
    int gi = blockIdx.x, t = threadIdx.x;
    sg[t] = g[gi * 64 + t];
    __syncthreads();
    float a = fc1b[t];
    for (int k = 0; k < 64; k++) a = fmaf(sg[k], fc1W[t * 64 + k], a);
    sg1[t] = fmaxf(a, 0.f);
    __syncthreads();
    if (t < 16) {
        float o = fc2b[t];
        for (int k = 0; k < 64; k++) o = fmaf(sg1[k], fc2W[t * 64 + k], o);
        out[gi * 16 + t] = o;
    }
}

// ---------------------------------------------------------------- launcher
extern "C" void kernel_launch(void* const* d_in, const int* in_sizes, int n_in,
                              void* d_out, int out_size, void* d_ws, size_t ws_size,
                              hipStream_t stream) {
    const float* x       = (const float*)d_in[0];
    const int*   eidx    = (const int*)d_in[1];
    const int*   batch   = (const int*)d_in[2];
    const float* encW    = (const float*)d_in[3];
    const float* encb    = (const float*)d_in[4];
    const float* nnW1    = (const float*)d_in[5];
    const float* nnb1    = (const float*)d_in[6];
    const float* nnW2    = (const float*)d_in[7];
    const float* nnb2    = (const float*)d_in[8];
    const float* mlpW    = (const float*)d_in[9];
    const float* mlpb    = (const float*)d_in[10];
    const float* bnG     = (const float*)d_in[11];
    const float* bnB     = (const float*)d_in[12];
    const float* fc1W    = (const float*)d_in[13];
    const float* fc1b    = (const float*)d_in[14];
    const float* fc2W    = (const float*)d_in[15];
    const float* fc2b    = (const float*)d_in[16];
    float* out = (float*)d_out;

    const int N = in_sizes[0] / 64;
    const int E = in_sizes[1] / 2;
    const int G = 512;
    const int* src = eidx;
    const int* dst = eidx + E;

    // workspace layout
    char* ws = (char*)d_ws;
    size_t off = 0;
    auto alloc = [&](size_t bytes) { size_t r = off; off = (off + bytes + 255) & ~(size_t)255; return r; };
    int*   deg     = (int*)(ws + alloc((size_t)(N + 1) * 4));
    int*   rowptr  = (int*)(ws + alloc((size_t)(N + 1) * 4));
    int*   bsums   = (int*)(ws + alloc(1024 * 4));
    int*   fill    = (int*)(ws + alloc((size_t)N * 4));
    int*   col     = (int*)(ws + alloc((size_t)E * 4));
    float* cnt     = (float*)(ws + alloc((size_t)N * 4));
    float* h0      = (float*)(ws + alloc((size_t)N * 64 * 4));
    unsigned short* baseH = (unsigned short*)(ws + alloc((size_t)N * 256 * 2 + 131072));  // +pad for OOB tile reads
    unsigned short* baseL = (unsigned short*)(ws + alloc((size_t)N * 256 * 2 + 131072));
    float* hA      = (float*)(ws + alloc((size_t)N * 64 * 4));
    float* hB      = (float*)(ws + alloc((size_t)N * 64 * 4));
    unsigned short* mWH = (unsigned short*)(ws + alloc((size_t)5 * 64 * 768 * 2));
    unsigned short* mWL = (unsigned short*)(ws + alloc((size_t)5 * 64 * 768 * 2));
    float* bnstats = (float*)(ws + alloc(5 * 128 * 4));
    float* gpool   = (float*)(ws + alloc((size_t)G * 64 * 4));

    hipMemsetAsync(deg, 0, (size_t)(N + 1) * 4, stream);
    hipMemsetAsync(fill, 0, (size_t)N * 4, stream);
    hipMemsetAsync(bnstats, 0, 5 * 128 * 4, stream);
    hipMemsetAsync(gpool, 0, (size_t)G * 64 * 4, stream);

    int egrid = (E + 255) / 256;
    int total = N + 1;
    int nscan = (total + SCAN_B - 1) / SCAN_B;
    int ngrid64 = (N + 63) / 64;
    int ngrid128 = (N + 127) / 128;

    k_degree<<<egrid, 256, 0, stream>>>(dst, deg, E);
    k_scan_block<<<nscan, SCAN_B, 0, stream>>>(deg, rowptr, bsums, total);
    k_scan_tops<<<1, SCAN_B, 0, stream>>>(bsums, nscan);
    k_scan_add<<<nscan, SCAN_B, 0, stream>>>(rowptr, bsums, total);
    k_fill<<<egrid, 256, 0, stream>>>(src, dst, rowptr, fill, col, E);

    // cast all 5 layers' mlpW to bf16 hi/lo (5*64*768 = 245760 floats = 61440 float4)
    k_castw<<<240, 256, 0, stream>>>(mlpW, mWH, mWL, 61440);

    // encoder: h0 = x @ encW.T + encb
    k_gemm64<false, false><<<ngrid64, 256, 0, stream>>>(x, encW, encb, h0, nullptr, N);

    for (int i = 0; i < 5; i++) {
        k_agg<<<(N + 3) / 4, 256, 0, stream>>>(h0, rowptr, col, baseH, baseL, cnt, N);
        k_gemm1<<<ngrid128, 256, 0, stream>>>(baseH, baseL, cnt,
                                              mWH + (size_t)i * 64 * 768,
                                              mWL + (size_t)i * 64 * 768,
                                              mlpb + i * 64, h0, hA, N);
        k_gemm64<true, false><<<ngrid64, 256, 0, stream>>>(hA, nnW1 + (size_t)i * 4096,
                                                           nnb1 + i * 64, hB, nullptr, N);
        k_gemm64<true, true><<<ngrid64, 256, 0, stream>>>(hB, nnW2 + (size_t)i * 4096,
                                                          nnb2 + i * 64, hA, bnstats + i * 128, N);
        k_bn<<<(N * 64 + 255) / 256, 256, 0, stream>>>(hA, bnstats + i * 128, bnG + i * 64,
                                                       bnB + i * 64, h0, N * 64, 1.f / (float)N);
    }

    k_pool<<<(N + 31) / 32, 256, 0, stream>>>(h0, batch, gpool, N);
    k_head<<<G, 64, 0, stream>>>(gpool, fc1W, fc1b, fc2W, fc2b, out);
}

// Round 6
// 1398.884 us; speedup vs baseline: 9.4738x; 1.1757x over previous
//
#include <hip/hip_runtime.h>
#include <hip/hip_bf16.h>

#define DELTA 2.5749f
#define BN_EPS 1e-5f

typedef __attribute__((ext_vector_type(8))) short bf16x8;
typedef __attribute__((ext_vector_type(4))) float f32x4;

__device__ inline unsigned short f2bf(float f) {
    union { float f; unsigned int u; } v; v.f = f;
    unsigned int r = v.u + 0x7fff + ((v.u >> 16) & 1);  // RNE
    return (unsigned short)(r >> 16);
}
__device__ inline float bf2f(unsigned short h) {
    union { unsigned int u; float f; } v; v.u = ((unsigned int)h) << 16;
    return v.f;
}

// ---------------------------------------------------------------- CSR build
__global__ void k_degree(const int* __restrict__ dst, int* __restrict__ deg, int E) {
    int e = blockIdx.x * 256 + threadIdx.x;
    if (e < E) atomicAdd(&deg[dst[e]], 1);
}

#define SCAN_B 1024
__global__ void k_scan_block(const int* __restrict__ deg, int* __restrict__ excl,
                             int* __restrict__ bsums, int total) {
    __shared__ int s[SCAN_B];
    int t = threadIdx.x, i = blockIdx.x * SCAN_B + t;
    int v = (i < total) ? deg[i] : 0;
    s[t] = v; __syncthreads();
    for (int off = 1; off < SCAN_B; off <<= 1) {
        int x = (t >= off) ? s[t - off] : 0;
        __syncthreads();
        s[t] += x;
        __syncthreads();
    }
    if (i < total) excl[i] = s[t] - v;
    if (t == SCAN_B - 1) bsums[blockIdx.x] = s[t];
}

__global__ void k_scan_tops(int* __restrict__ bsums, int nb) {
    __shared__ int s[SCAN_B];
    int t = threadIdx.x;
    int v = (t < nb) ? bsums[t] : 0;
    s[t] = v; __syncthreads();
    for (int off = 1; off < SCAN_B; off <<= 1) {
        int x = (t >= off) ? s[t - off] : 0;
        __syncthreads();
        s[t] += x;
        __syncthreads();
    }
    if (t < nb) bsums[t] = s[t] - v;  // exclusive
}

__global__ void k_scan_add(int* __restrict__ excl, const int* __restrict__ bsums, int total) {
    int i = blockIdx.x * SCAN_B + threadIdx.x;
    if (i < total) excl[i] += bsums[blockIdx.x];
}

__global__ void k_fill(const int* __restrict__ src, const int* __restrict__ dst,
                       const int* __restrict__ rowptr, int* __restrict__ fill,
                       int* __restrict__ col, int E) {
    int e = blockIdx.x * 256 + threadIdx.x;
    if (e < E) {
        int d = dst[e];
        int pos = rowptr[d] + atomicAdd(&fill[d], 1);
        col[pos] = src[e];
    }
}

// ---------------------------------------------------------------- weight cast f32 -> bf16 hi/lo planes
__global__ void k_castw(const float* __restrict__ w, unsigned short* __restrict__ oh,
                        unsigned short* __restrict__ ol, int n4) {
    int i = blockIdx.x * 256 + threadIdx.x;
    if (i < n4) {
        float4 v = ((const float4*)w)[i];
        ushort4 rh, rl;
        rh.x = f2bf(v.x); rl.x = f2bf(v.x - bf2f(rh.x));
        rh.y = f2bf(v.y); rl.y = f2bf(v.y - bf2f(rh.y));
        rh.z = f2bf(v.z); rl.z = f2bf(v.z - bf2f(rh.z));
        rh.w = f2bf(v.w); rl.w = f2bf(v.w - bf2f(rh.w));
        ((ushort4*)oh)[i] = rh;
        ((ushort4*)ol)[i] = rl;
    }
}

// ---------------------------------------------------------------- aggregation
__global__ __launch_bounds__(256) void k_agg(const float* __restrict__ h,
                                             const int* __restrict__ rowptr,
                                             const int* __restrict__ col,
                                             unsigned short* __restrict__ baseH,
                                             unsigned short* __restrict__ baseL,
                                             float* __restrict__ cnt, int N) {
    int node = blockIdx.x * 4 + (threadIdx.x >> 6);
    int lane = threadIdx.x & 63;
    if (node >= N) return;
    int slot = lane >> 4;        // which of 4 concurrent edges
    int fo = (lane & 15) * 4;    // feature offset
    int s0 = rowptr[node], s1 = rowptr[node + 1];
    int deg = s1 - s0;
    float4 sum = make_float4(0.f, 0.f, 0.f, 0.f);
    float4 sq = sum;
    float4 mx = make_float4(-INFINITY, -INFINITY, -INFINITY, -INFINITY);
    int e = s0 + slot;
    for (; e + 4 < s1; e += 8) {
        int sA = col[e], sB = col[e + 4];
        float4 v1 = *(const float4*)(h + (size_t)sA * 64 + fo);
        float4 v2 = *(const float4*)(h + (size_t)sB * 64 + fo);
        sum.x += v1.x; sum.y += v1.y; sum.z += v1.z; sum.w += v1.w;
        sq.x = fmaf(v1.x, v1.x, sq.x); sq.y = fmaf(v1.y, v1.y, sq.y);
        sq.z = fmaf(v1.z, v1.z, sq.z); sq.w = fmaf(v1.w, v1.w, sq.w);
        mx.x = fmaxf(mx.x, v1.x); mx.y = fmaxf(mx.y, v1.y);
        mx.z = fmaxf(mx.z, v1.z); mx.w = fmaxf(mx.w, v1.w);
        sum.x += v2.x; sum.y += v2.y; sum.z += v2.z; sum.w += v2.w;
        sq.x = fmaf(v2.x, v2.x, sq.x); sq.y = fmaf(v2.y, v2.y, sq.y);
        sq.z = fmaf(v2.z, v2.z, sq.z); sq.w = fmaf(v2.w, v2.w, sq.w);
        mx.x = fmaxf(mx.x, v2.x); mx.y = fmaxf(mx.y, v2.y);
        mx.z = fmaxf(mx.z, v2.z); mx.w = fmaxf(mx.w, v2.w);
    }
    if (e < s1) {
        int s = col[e];
        float4 v = *(const float4*)(h + (size_t)s * 64 + fo);
        sum.x += v.x; sum.y += v.y; sum.z += v.z; sum.w += v.w;
        sq.x = fmaf(v.x, v.x, sq.x); sq.y = fmaf(v.y, v.y, sq.y);
        sq.z = fmaf(v.z, v.z, sq.z); sq.w = fmaf(v.w, v.w, sq.w);
        mx.x = fmaxf(mx.x, v.x); mx.y = fmaxf(mx.y, v.y);
        mx.z = fmaxf(mx.z, v.z); mx.w = fmaxf(mx.w, v.w);
    }
#pragma unroll
    for (int m = 16; m <= 32; m <<= 1) {
        sum.x += __shfl_xor(sum.x, m); sum.y += __shfl_xor(sum.y, m);
        sum.z += __shfl_xor(sum.z, m); sum.w += __shfl_xor(sum.w, m);
        sq.x += __shfl_xor(sq.x, m); sq.y += __shfl_xor(sq.y, m);
        sq.z += __shfl_xor(sq.z, m); sq.w += __shfl_xor(sq.w, m);
        mx.x = fmaxf(mx.x, __shfl_xor(mx.x, m)); mx.y = fmaxf(mx.y, __shfl_xor(mx.y, m));
        mx.z = fmaxf(mx.z, __shfl_xor(mx.z, m)); mx.w = fmaxf(mx.w, __shfl_xor(mx.w, m));
    }
    float c = (float)(deg > 0 ? deg : 1);
    float ic = 1.f / c;
    float4 mean = make_float4(sum.x * ic, sum.y * ic, sum.z * ic, sum.w * ic);
    float4 var = make_float4(fmaxf(fmaf(-mean.x, mean.x, sq.x * ic), 0.f),
                             fmaxf(fmaf(-mean.y, mean.y, sq.y * ic), 0.f),
                             fmaxf(fmaf(-mean.z, mean.z, sq.z * ic), 0.f),
                             fmaxf(fmaf(-mean.w, mean.w, sq.w * ic), 0.f));
    if (deg == 0) mx = make_float4(0.f, 0.f, 0.f, 0.f);
    float4 wv = (slot == 0) ? sum : (slot == 1) ? mx : (slot == 2) ? mean : var;
    ushort4 oh, ol;
    oh.x = f2bf(wv.x); ol.x = f2bf(wv.x - bf2f(oh.x));
    oh.y = f2bf(wv.y); ol.y = f2bf(wv.y - bf2f(oh.y));
    oh.z = f2bf(wv.z); ol.z = f2bf(wv.z - bf2f(oh.z));
    oh.w = f2bf(wv.w); ol.w = f2bf(wv.w - bf2f(oh.w));
    size_t boff = (size_t)node * 256 + slot * 64 + fo;
    *(ushort4*)(baseH + boff) = oh;
    *(ushort4*)(baseL + boff) = ol;
    if (lane == 0) cnt[node] = c;
}

// ---------------------------------------------------------------- big GEMM via MFMA bf16 split-precision
// Weights staged per 64-k chunk into LDS in per-lane fragment order (48 records x 1KB = 48KB).
// Block = 256 thr = 4 waves x 32 nodes = 128 nodes. 3 blocks/CU; staging overlaps via other blocks.
__global__ __launch_bounds__(256) void k_gemm1(const unsigned short* __restrict__ baseH,
                                               const unsigned short* __restrict__ baseL,
                                               const float* __restrict__ cnt,
                                               const unsigned short* __restrict__ mWH,
                                               const unsigned short* __restrict__ mWL,
                                               const float* __restrict__ mb,
                                               const float* __restrict__ hres,
                                               float* __restrict__ out, int N) {
    __shared__ unsigned short ldsW[48 * 512];  // 48 records x 1KB (rec = (s*2+p)*12 + mat*4 + nt)
    int t = threadIdx.x;
    int wave = t >> 6, lane = t & 63;
    int r16 = lane & 15, quad = lane >> 4;
    int m0 = blockIdx.x * 128 + wave * 32;   // first m-tile; second is m0+16
    size_t aoff0 = (size_t)(m0 + r16) * 256 + quad * 8;
    size_t aoff1 = (size_t)(m0 + 16 + r16) * 256 + quad * 8;

    f32x4 acc0[12], acc1[12];
#pragma unroll
    for (int i = 0; i < 12; i++) {
        acc0[i] = (f32x4){0.f, 0.f, 0.f, 0.f};
        acc1[i] = (f32x4){0.f, 0.f, 0.f, 0.f};
    }

#pragma unroll 1
    for (int chunk = 0; chunk < 4; chunk++) {
        if (chunk) __syncthreads();  // prior compute done before overwrite
        // stage this chunk's weights, pre-swizzled: each thread fills 12 record-slots
#pragma unroll
        for (int rb = 0; rb < 48; rb += 4) {
            int rec = rb + wave;
            int s = rec / 24, p = (rec / 12) & 1, tile = rec % 12;
            int mat = tile >> 2, nt = tile & 3;
            const unsigned short* pl = p ? mWL : mWH;
            uint4 v = *(const uint4*)(pl + (size_t)(nt * 16 + r16) * 768 + mat * 256
                                      + chunk * 64 + s * 32 + quad * 8);
            *(uint4*)(ldsW + rec * 512 + lane * 8) = v;
        }
        __syncthreads();
#pragma unroll
        for (int s = 0; s < 2; s++) {
            int ks = chunk * 64 + s * 32;
            bf16x8 aH0 = *(const bf16x8*)(baseH + aoff0 + ks);
            bf16x8 aL0 = *(const bf16x8*)(baseL + aoff0 + ks);
            bf16x8 aH1 = *(const bf16x8*)(baseH + aoff1 + ks);
            bf16x8 aL1 = *(const bf16x8*)(baseL + aoff1 + ks);
#pragma unroll
            for (int tile = 0; tile < 12; tile++) {
                bf16x8 wH = *(const bf16x8*)(ldsW + ((s * 2 + 0) * 12 + tile) * 512 + lane * 8);
                bf16x8 wL = *(const bf16x8*)(ldsW + ((s * 2 + 1) * 12 + tile) * 512 + lane * 8);
                acc0[tile] = __builtin_amdgcn_mfma_f32_16x16x32_bf16(aH0, wH, acc0[tile], 0, 0, 0);
                acc1[tile] = __builtin_amdgcn_mfma_f32_16x16x32_bf16(aH1, wH, acc1[tile], 0, 0, 0);
                acc0[tile] = __builtin_amdgcn_mfma_f32_16x16x32_bf16(aL0, wH, acc0[tile], 0, 0, 0);
                acc1[tile] = __builtin_amdgcn_mfma_f32_16x16x32_bf16(aL1, wH, acc1[tile], 0, 0, 0);
                acc0[tile] = __builtin_amdgcn_mfma_f32_16x16x32_bf16(aH0, wL, acc0[tile], 0, 0, 0);
                acc1[tile] = __builtin_amdgcn_mfma_f32_16x16x32_bf16(aH1, wL, acc1[tile], 0, 0, 0);
            }
        }
    }
    // epilogue: D row = quad*4+reg (node within tile), col = r16 (feat within n-tile)
#pragma unroll
    for (int mt = 0; mt < 2; mt++) {
#pragma unroll
        for (int i = 0; i < 4; i++) {
            int node = m0 + mt * 16 + quad * 4 + i;
            if (node < N) {
                float c = cnt[node];
                float amp = c / DELTA, att = DELTA / c;
#pragma unroll
                for (int nt = 0; nt < 4; nt++) {
                    int feat = nt * 16 + r16;
                    f32x4* a = mt ? acc1 : acc0;
                    float v = a[nt][i] + amp * a[4 + nt][i] + att * a[8 + nt][i]
                            + mb[feat] + hres[(size_t)node * 64 + feat];
                    out[(size_t)node * 64 + feat] = v;
                }
            }
        }
    }
}

// ---------------------------------------------------------------- 64x64 GEMM (encoder / nn1 / nn2)
#define FMA16(ACC0, ACC1, ACC2, ACC3, A, W)                                \
    do {                                                                   \
        ACC0.x = fmaf(A.x, W.x, ACC0.x); ACC0.y = fmaf(A.x, W.y, ACC0.y);  \
        ACC0.z = fmaf(A.x, W.z, ACC0.z); ACC0.w = fmaf(A.x, W.w, ACC0.w);  \
        ACC1.x = fmaf(A.y, W.x, ACC1.x); ACC1.y = fmaf(A.y, W.y, ACC1.y);  \
        ACC1.z = fmaf(A.y, W.z, ACC1.z); ACC1.w = fmaf(A.y, W.w, ACC1.w);  \
        ACC2.x = fmaf(A.z, W.x, ACC2.x); ACC2.y = fmaf(A.z, W.y, ACC2.y);  \
        ACC2.z = fmaf(A.z, W.z, ACC2.z); ACC2.w = fmaf(A.z, W.w, ACC2.w);  \
        ACC3.x = fmaf(A.w, W.x, ACC3.x); ACC3.y = fmaf(A.w, W.y, ACC3.y);  \
        ACC3.z = fmaf(A.w, W.z, ACC3.z); ACC3.w = fmaf(A.w, W.w, ACC3.w);  \
    } while (0)

template <bool RELU, bool BNSTAT>
__global__ __launch_bounds__(256) void k_gemm64(const float* __restrict__ in,
                                                const float* __restrict__ W,
                                                const float* __restrict__ bias,
                                                float* __restrict__ out,
                                                float* __restrict__ bnstat, int N) {
    __shared__ float sInT[64][64];  // [k][node]
    __shared__ float sWT[64][64];   // [k][feat]
    int t = threadIdx.x;
    int tx = t & 15, ty = t >> 4;
    int n0 = blockIdx.x * 64;
    int c4 = tx * 4;
#pragma unroll
    for (int ch = 0; ch < 4; ch++) {
        int row = ch * 16 + ty;
        float4 v = make_float4(0.f, 0.f, 0.f, 0.f);
        if (n0 + row < N) v = *(const float4*)(in + (size_t)(n0 + row) * 64 + c4);
        sInT[c4 + 0][row] = v.x; sInT[c4 + 1][row] = v.y;
        sInT[c4 + 2][row] = v.z; sInT[c4 + 3][row] = v.w;
        float4 w = *(const float4*)(W + (size_t)row * 64 + c4);
        sWT[c4 + 0][row] = w.x; sWT[c4 + 1][row] = w.y;
        sWT[c4 + 2][row] = w.z; sWT[c4 + 3][row] = w.w;
    }
    __syncthreads();
    float4 acc0 = make_float4(0.f, 0.f, 0.f, 0.f);
    float4 acc1 = acc0, acc2 = acc0, acc3 = acc0;
#pragma unroll 8
    for (int k = 0; k < 64; k++) {
        float4 a = *(const float4*)(&sInT[k][ty * 4]);
        float4 w = *(const float4*)(&sWT[k][tx * 4]);
        FMA16(acc0, acc1, acc2, acc3, a, w);
    }
    float4 b4 = *(const float4*)(bias + tx * 4);
    float4 s1 = make_float4(0.f, 0.f, 0.f, 0.f);
    float4 s2 = s1;
#pragma unroll
    for (int i = 0; i < 4; i++) {
        int n = n0 + ty * 4 + i;
        if (n < N) {
            float4 v = (i == 0) ? acc0 : (i == 1) ? acc1 : (i == 2) ? acc2 : acc3;
            v.x += b4.x; v.y += b4.y; v.z += b4.z; v.w += b4.w;
            if (RELU) {
                v.x = fmaxf(v.x, 0.f); v.y = fmaxf(v.y, 0.f);
                v.z = fmaxf(v.z, 0.f); v.w = fmaxf(v.w, 0.f);
            }
            *(float4*)(out + (size_t)n * 64 + tx * 4) = v;
            if (BNSTAT) {
                s1.x += v.x; s1.y += v.y; s1.z += v.z; s1.w += v.w;
                s2.x = fmaf(v.x, v.x, s2.x); s2.y = fmaf(v.y, v.y, s2.y);
                s2.z = fmaf(v.z, v.z, s2.z); s2.w = fmaf(v.w, v.w, s2.w);
            }
        }
    }
    if (BNSTAT) {
        __syncthreads();
        float* red = &sInT[0][0];
        *(float4*)(red + ty * 64 + tx * 4) = s1;
        *(float4*)(red + 1024 + ty * 64 + tx * 4) = s2;
        __syncthreads();
        if (t < 128) {
            int d = t & 63;
            int base = (t >> 6) * 1024;
            float tot = 0.f;
#pragma unroll
            for (int r2 = 0; r2 < 16; r2++) tot += red[base + r2 * 64 + d];
            atomicAdd(&bnstat[(t >> 6) * 64 + d], tot);
        }
    }
}

// ---------------------------------------------------------------- batchnorm apply
__global__ void k_bn(const float* __restrict__ in, const float* __restrict__ stat,
                     const float* __restrict__ gamma, const float* __restrict__ beta,
                     float* __restrict__ outh, int total, float invN) {
    int idx = blockIdx.x * 256 + threadIdx.x;
    if (idx >= total) return;
    int d = idx & 63;
    float mu = stat[d] * invN;
    float var = stat[64 + d] * invN - mu * mu;
    float sc = rsqrtf(var + BN_EPS) * gamma[d];
    outh[idx] = (in[idx] - mu) * sc + beta[d];
}

// ---------------------------------------------------------------- pool (batch is sorted)
__global__ void k_pool(const float* __restrict__ h, const int* __restrict__ batch,
                       float* __restrict__ g, int N) {
    int d = threadIdx.x & 63, r = threadIdx.x >> 6;
    int nbase = blockIdx.x * 32;
    float acc = 0.f;
    int gcur = -1;
    for (int i = 0; i < 8; i++) {
        int n = nbase + i * 4 + r;
        if (n < N) {
            int gb = batch[n];
            if (gb != gcur) {
                if (gcur >= 0) atomicAdd(&g[gcur * 64 + d], acc);
                acc = 0.f; gcur = gb;
            }
            acc += h[(size_t)n * 64 + d];
        }
    }
    if (gcur >= 0) atomicAdd(&g[gcur * 64 + d], acc);
}

// ---------------------------------------------------------------- head: relu(g@fc1)+fc2
__global__ void k_head(const float* __restrict__ g, const float* __restrict__ fc1W,
                       const float* __restrict__ fc1b, const float* __restrict__ fc2W,
                       const float* __restrict__ fc2b, float* __restrict__ out) {
    __shared__ float sg[64], sg1[64];
    int gi = blockIdx.x, t = threadIdx.x;
    sg[t] = g[gi * 64 + t];
    __syncthreads();
    float a = fc1b[t];
    for (int k = 0; k < 64; k++) a = fmaf(sg[k], fc1W[t * 64 + k], a);
    sg1[t] = fmaxf(a, 0.f);
    __syncthreads();
    if (t < 16) {
        float o = fc2b[t];
        for (int k = 0; k < 64; k++) o = fmaf(sg1[k], fc2W[t * 64 + k], o);
        out[gi * 16 + t] = o;
    }
}

// ---------------------------------------------------------------- launcher
extern "C" void kernel_launch(void* const* d_in, const int* in_sizes, int n_in,
                              void* d_out, int out_size, void* d_ws, size_t ws_size,
                              hipStream_t stream) {
    const float* x       = (const float*)d_in[0];
    const int*   eidx    = (const int*)d_in[1];
    const int*   batch   = (const int*)d_in[2];
    const float* encW    = (const float*)d_in[3];
    const float* encb    = (const float*)d_in[4];
    const float* nnW1    = (const float*)d_in[5];
    const float* nnb1    = (const float*)d_in[6];
    const float* nnW2    = (const float*)d_in[7];
    const float* nnb2    = (const float*)d_in[8];
    const float* mlpW    = (const float*)d_in[9];
    const float* mlpb    = (const float*)d_in[10];
    const float* bnG     = (const float*)d_in[11];
    const float* bnB     = (const float*)d_in[12];
    const float* fc1W    = (const float*)d_in[13];
    const float* fc1b    = (const float*)d_in[14];
    const float* fc2W    = (const float*)d_in[15];
    const float* fc2b    = (const float*)d_in[16];
    float* out = (float*)d_out;

    const int N = in_sizes[0] / 64;
    const int E = in_sizes[1] / 2;
    const int G = 512;
    const int* src = eidx;
    const int* dst = eidx + E;

    // workspace layout
    char* ws = (char*)d_ws;
    size_t off = 0;
    auto alloc = [&](size_t bytes) { size_t r = off; off = (off + bytes + 255) & ~(size_t)255; return r; };
    int*   deg     = (int*)(ws + alloc((size_t)(N + 1) * 4));
    int*   rowptr  = (int*)(ws + alloc((size_t)(N + 1) * 4));
    int*   bsums   = (int*)(ws + alloc(1024 * 4));
    int*   fill    = (int*)(ws + alloc((size_t)N * 4));
    int*   col     = (int*)(ws + alloc((size_t)E * 4));
    float* cnt     = (float*)(ws + alloc((size_t)N * 4));
    float* h0      = (float*)(ws + alloc((size_t)N * 64 * 4));
    unsigned short* baseH = (unsigned short*)(ws + alloc((size_t)N * 256 * 2 + 131072));  // +pad for OOB tile reads
    unsigned short* baseL = (unsigned short*)(ws + alloc((size_t)N * 256 * 2 + 131072));
    float* hA      = (float*)(ws + alloc((size_t)N * 64 * 4));
    float* hB      = (float*)(ws + alloc((size_t)N * 64 * 4));
    unsigned short* mWH = (unsigned short*)(ws + alloc((size_t)5 * 64 * 768 * 2));
    unsigned short* mWL = (unsigned short*)(ws + alloc((size_t)5 * 64 * 768 * 2));
    float* bnstats = (float*)(ws + alloc(5 * 128 * 4));
    float* gpool   = (float*)(ws + alloc((size_t)G * 64 * 4));

    hipMemsetAsync(deg, 0, (size_t)(N + 1) * 4, stream);
    hipMemsetAsync(fill, 0, (size_t)N * 4, stream);
    hipMemsetAsync(bnstats, 0, 5 * 128 * 4, stream);
    hipMemsetAsync(gpool, 0, (size_t)G * 64 * 4, stream);

    int egrid = (E + 255) / 256;
    int total = N + 1;
    int nscan = (total + SCAN_B - 1) / SCAN_B;
    int ngrid64 = (N + 63) / 64;
    int ngrid128 = (N + 127) / 128;

    k_degree<<<egrid, 256, 0, stream>>>(dst, deg, E);
    k_scan_block<<<nscan, SCAN_B, 0, stream>>>(deg, rowptr, bsums, total);
    k_scan_tops<<<1, SCAN_B, 0, stream>>>(bsums, nscan);
    k_scan_add<<<nscan, SCAN_B, 0, stream>>>(rowptr, bsums, total);
    k_fill<<<egrid, 256, 0, stream>>>(src, dst, rowptr, fill, col, E);

    // cast all 5 layers' mlpW to bf16 hi/lo (5*64*768 = 245760 floats = 61440 float4)
    k_castw<<<240, 256, 0, stream>>>(mlpW, mWH, mWL, 61440);

    // encoder: h0 = x @ encW.T + encb
    k_gemm64<false, false><<<ngrid64, 256, 0, stream>>>(x, encW, encb, h0, nullptr, N);

    for (int i = 0; i < 5; i++) {
        k_agg<<<(N + 3) / 4, 256, 0, stream>>>(h0, rowptr, col, baseH, baseL, cnt, N);
        k_gemm1<<<ngrid128, 256, 0, stream>>>(baseH, baseL, cnt,
                                              mWH + (size_t)i * 64 * 768,
                                              mWL + (size_t)i * 64 * 768,
                                              mlpb + i * 64, h0, hA, N);
        k_gemm64<true, false><<<ngrid64, 256, 0, stream>>>(hA, nnW1 + (size_t)i * 4096,
                                                           nnb1 + i * 64, hB, nullptr, N);
        k_gemm64<true, true><<<ngrid64, 256, 0, stream>>>(hB, nnW2 + (size_t)i * 4096,
                                                          nnb2 + i * 64, hA, bnstats + i * 128, N);
        k_bn<<<(N * 64 + 255) / 256, 256, 0, stream>>>(hA, bnstats + i * 128, bnG + i * 64,
                                                       bnB + i * 64, h0, N * 64, 1.f / (float)N);
    }

    k_pool<<<(N + 31) / 32, 256, 0, stream>>>(h0, batch, gpool, N);
    k_head<<<G, 64, 0, stream>>>(gpool, fc1W, fc1b, fc2W, fc2b, out);
}

// Round 7
// 1338.573 us; speedup vs baseline: 9.9007x; 1.0451x over previous
//
#include <hip/hip_runtime.h>
#include <hip/hip_bf16.h>

#define DELTA 2.5749f
#define BN_EPS 1e-5f

typedef __attribute__((ext_vector_type(8))) short bf16x8;
typedef __attribute__((ext_vector_type(4))) float f32x4;

__device__ inline unsigned short f2bf(float f) {
    union { float f; unsigned int u; } v; v.f = f;
    unsigned int r = v.u + 0x7fff + ((v.u >> 16) & 1);  // RNE
    return (unsigned short)(r >> 16);
}
__device__ inline float bf2f(unsigned short h) {
    union { unsigned int u; float f; } v; v.u = ((unsigned int)h) << 16;
    return v.f;
}

// ---------------------------------------------------------------- CSR build (XCD-partitioned)
// partition p = blockIdx.x & 7 handles dst in [p*npp, (p+1)*npp): scatter stays XCD-local
__global__ __launch_bounds__(256) void k_degree(const int* __restrict__ dst,
                                                int* __restrict__ deg, int E, int npp) {
    int part = blockIdx.x & 7;
    int lo = part * npp, hi = lo + npp;
    int stride = (gridDim.x >> 3) * 256;
    for (int e = (blockIdx.x >> 3) * 256 + threadIdx.x; e < E; e += stride) {
        int d = dst[e];
        if (d >= lo && d < hi) atomicAdd(&deg[d], 1);
    }
}

#define SCAN_B 1024
__global__ void k_scan_block(const int* __restrict__ deg, int* __restrict__ excl,
                             int* __restrict__ bsums, int total) {
    __shared__ int s[SCAN_B];
    int t = threadIdx.x, i = blockIdx.x * SCAN_B + t;
    int v = (i < total) ? deg[i] : 0;
    s[t] = v; __syncthreads();
    for (int off = 1; off < SCAN_B; off <<= 1) {
        int x = (t >= off) ? s[t - off] : 0;
        __syncthreads();
        s[t] += x;
        __syncthreads();
    }
    if (i < total) excl[i] = s[t] - v;
    if (t == SCAN_B - 1) bsums[blockIdx.x] = s[t];
}

__global__ void k_scan_tops(int* __restrict__ bsums, int nb) {
    __shared__ int s[SCAN_B];
    int t = threadIdx.x;
    int v = (t < nb) ? bsums[t] : 0;
    s[t] = v; __syncthreads();
    for (int off = 1; off < SCAN_B; off <<= 1) {
        int x = (t >= off) ? s[t - off] : 0;
        __syncthreads();
        s[t] += x;
        __syncthreads();
    }
    if (t < nb) bsums[t] = s[t] - v;  // exclusive
}

__global__ void k_scan_add(int* __restrict__ excl, const int* __restrict__ bsums, int total) {
    int i = blockIdx.x * SCAN_B + threadIdx.x;
    if (i < total) excl[i] += bsums[blockIdx.x];
}

__global__ __launch_bounds__(256) void k_fill(const int* __restrict__ src,
                                              const int* __restrict__ dst,
                                              const int* __restrict__ rowptr,
                                              int* __restrict__ fill,
                                              int* __restrict__ col, int E, int npp) {
    int part = blockIdx.x & 7;
    int lo = part * npp, hi = lo + npp;
    int stride = (gridDim.x >> 3) * 256;
    for (int e = (blockIdx.x >> 3) * 256 + threadIdx.x; e < E; e += stride) {
        int d = dst[e];
        if (d >= lo && d < hi) {
            int pos = rowptr[d] + atomicAdd(&fill[d], 1);
            col[pos] = src[e];
        }
    }
}

// ---------------------------------------------------------------- weight cast f32 -> bf16 hi/lo planes
__global__ void k_castw(const float* __restrict__ w, unsigned short* __restrict__ oh,
                        unsigned short* __restrict__ ol, int n4) {
    int i = blockIdx.x * 256 + threadIdx.x;
    if (i < n4) {
        float4 v = ((const float4*)w)[i];
        ushort4 rh, rl;
        rh.x = f2bf(v.x); rl.x = f2bf(v.x - bf2f(rh.x));
        rh.y = f2bf(v.y); rl.y = f2bf(v.y - bf2f(rh.y));
        rh.z = f2bf(v.z); rl.z = f2bf(v.z - bf2f(rh.z));
        rh.w = f2bf(v.w); rl.w = f2bf(v.w - bf2f(rh.w));
        ((ushort4*)oh)[i] = rh;
        ((ushort4*)ol)[i] = rl;
    }
}

// ---------------------------------------------------------------- BN affine helpers
__global__ void k_ident(float* __restrict__ aff) {
    int t = threadIdx.x;  // 128
    aff[t] = (t < 64) ? 1.f : 0.f;
}

__global__ void k_bnfin(const float* __restrict__ stat, const float* __restrict__ gamma,
                        const float* __restrict__ beta, float* __restrict__ aff, float invN) {
    int d = threadIdx.x;  // 64
    float mu = stat[d] * invN;
    float var = stat[64 + d] * invN - mu * mu;
    float sc = rsqrtf(var + BN_EPS) * gamma[d];
    aff[d] = sc;
    aff[64 + d] = beta[d] - mu * sc;
}

// ---------------------------------------------------------------- aggregation (BN fused, unroll 4)
// one wave per node; 16 lanes per edge (float4); 16 gathers in flight.
#define AGG_ACC(V)                                                         \
    do {                                                                   \
        V.x = fmaf(V.x, sc4.x, sh4.x); V.y = fmaf(V.y, sc4.y, sh4.y);      \
        V.z = fmaf(V.z, sc4.z, sh4.z); V.w = fmaf(V.w, sc4.w, sh4.w);      \
        sum.x += V.x; sum.y += V.y; sum.z += V.z; sum.w += V.w;            \
        sq.x = fmaf(V.x, V.x, sq.x); sq.y = fmaf(V.y, V.y, sq.y);          \
        sq.z = fmaf(V.z, V.z, sq.z); sq.w = fmaf(V.w, V.w, sq.w);          \
        mx.x = fmaxf(mx.x, V.x); mx.y = fmaxf(mx.y, V.y);                  \
        mx.z = fmaxf(mx.z, V.z); mx.w = fmaxf(mx.w, V.w);                  \
    } while (0)

__global__ __launch_bounds__(256) void k_agg(const float* __restrict__ h,
                                             const int* __restrict__ rowptr,
                                             const int* __restrict__ col,
                                             const float* __restrict__ aff,
                                             unsigned short* __restrict__ baseH,
                                             unsigned short* __restrict__ baseL,
                                             float* __restrict__ cnt, int N) {
    int node = blockIdx.x * 4 + (threadIdx.x >> 6);
    int lane = threadIdx.x & 63;
    if (node >= N) return;
    int slot = lane >> 4;        // which of 4 concurrent edges
    int fo = (lane & 15) * 4;    // feature offset
    float4 sc4 = *(const float4*)(aff + fo);
    float4 sh4 = *(const float4*)(aff + 64 + fo);
    int s0 = rowptr[node], s1 = rowptr[node + 1];
    int deg = s1 - s0;
    float4 sum = make_float4(0.f, 0.f, 0.f, 0.f);
    float4 sq = sum;
    float4 mx = make_float4(-INFINITY, -INFINITY, -INFINITY, -INFINITY);
    int e = s0 + slot;
    for (; e + 12 < s1; e += 16) {
        int sA = col[e], sB = col[e + 4], sC = col[e + 8], sD = col[e + 12];
        float4 v1 = *(const float4*)(h + (size_t)sA * 64 + fo);
        float4 v2 = *(const float4*)(h + (size_t)sB * 64 + fo);
        float4 v3 = *(const float4*)(h + (size_t)sC * 64 + fo);
        float4 v4 = *(const float4*)(h + (size_t)sD * 64 + fo);
        AGG_ACC(v1); AGG_ACC(v2); AGG_ACC(v3); AGG_ACC(v4);
    }
    for (; e < s1; e += 4) {
        int s = col[e];
        float4 v = *(const float4*)(h + (size_t)s * 64 + fo);
        AGG_ACC(v);
    }
#pragma unroll
    for (int m = 16; m <= 32; m <<= 1) {
        sum.x += __shfl_xor(sum.x, m); sum.y += __shfl_xor(sum.y, m);
        sum.z += __shfl_xor(sum.z, m); sum.w += __shfl_xor(sum.w, m);
        sq.x += __shfl_xor(sq.x, m); sq.y += __shfl_xor(sq.y, m);
        sq.z += __shfl_xor(sq.z, m); sq.w += __shfl_xor(sq.w, m);
        mx.x = fmaxf(mx.x, __shfl_xor(mx.x, m)); mx.y = fmaxf(mx.y, __shfl_xor(mx.y, m));
        mx.z = fmaxf(mx.z, __shfl_xor(mx.z, m)); mx.w = fmaxf(mx.w, __shfl_xor(mx.w, m));
    }
    float c = (float)(deg > 0 ? deg : 1);
    float ic = 1.f / c;
    float4 mean = make_float4(sum.x * ic, sum.y * ic, sum.z * ic, sum.w * ic);
    float4 var = make_float4(fmaxf(fmaf(-mean.x, mean.x, sq.x * ic), 0.f),
                             fmaxf(fmaf(-mean.y, mean.y, sq.y * ic), 0.f),
                             fmaxf(fmaf(-mean.z, mean.z, sq.z * ic), 0.f),
                             fmaxf(fmaf(-mean.w, mean.w, sq.w * ic), 0.f));
    if (deg == 0) mx = make_float4(0.f, 0.f, 0.f, 0.f);
    float4 wv = (slot == 0) ? sum : (slot == 1) ? mx : (slot == 2) ? mean : var;
    ushort4 oh, ol;
    oh.x = f2bf(wv.x); ol.x = f2bf(wv.x - bf2f(oh.x));
    oh.y = f2bf(wv.y); ol.y = f2bf(wv.y - bf2f(oh.y));
    oh.z = f2bf(wv.z); ol.z = f2bf(wv.z - bf2f(oh.z));
    oh.w = f2bf(wv.w); ol.w = f2bf(wv.w - bf2f(oh.w));
    size_t boff = (size_t)node * 256 + slot * 64 + fo;
    *(ushort4*)(baseH + boff) = oh;
    *(ushort4*)(baseL + boff) = ol;
    if (lane == 0) cnt[node] = c;
}

// ---------------------------------------------------------------- big GEMM via MFMA bf16 split-precision
// Weights staged per 64-k chunk into LDS in per-lane fragment order (48 records x 1KB = 48KB).
// Residual applies BN affine to hres on the fly.
__global__ __launch_bounds__(256) void k_gemm1(const unsigned short* __restrict__ baseH,
                                               const unsigned short* __restrict__ baseL,
                                               const float* __restrict__ cnt,
                                               const unsigned short* __restrict__ mWH,
                                               const unsigned short* __restrict__ mWL,
                                               const float* __restrict__ mb,
                                               const float* __restrict__ hres,
                                               const float* __restrict__ aff,
                                               float* __restrict__ out, int N) {
    __shared__ unsigned short ldsW[48 * 512];  // rec = (s*2+p)*12 + mat*4 + nt
    int t = threadIdx.x;
    int wave = t >> 6, lane = t & 63;
    int r16 = lane & 15, quad = lane >> 4;
    int m0 = blockIdx.x * 128 + wave * 32;   // first m-tile; second is m0+16
    size_t aoff0 = (size_t)(m0 + r16) * 256 + quad * 8;
    size_t aoff1 = (size_t)(m0 + 16 + r16) * 256 + quad * 8;

    f32x4 acc0[12], acc1[12];
#pragma unroll
    for (int i = 0; i < 12; i++) {
        acc0[i] = (f32x4){0.f, 0.f, 0.f, 0.f};
        acc1[i] = (f32x4){0.f, 0.f, 0.f, 0.f};
    }

#pragma unroll 1
    for (int chunk = 0; chunk < 4; chunk++) {
        if (chunk) __syncthreads();
#pragma unroll
        for (int rb = 0; rb < 48; rb += 4) {
            int rec = rb + wave;
            int s = rec / 24, p = (rec / 12) & 1, tile = rec % 12;
            int mat = tile >> 2, nt = tile & 3;
            const unsigned short* pl = p ? mWL : mWH;
            uint4 v = *(const uint4*)(pl + (size_t)(nt * 16 + r16) * 768 + mat * 256
                                      + chunk * 64 + s * 32 + quad * 8);
            *(uint4*)(ldsW + rec * 512 + lane * 8) = v;
        }
        __syncthreads();
#pragma unroll
        for (int s = 0; s < 2; s++) {
            int ks = chunk * 64 + s * 32;
            bf16x8 aH0 = *(const bf16x8*)(baseH + aoff0 + ks);
            bf16x8 aL0 = *(const bf16x8*)(baseL + aoff0 + ks);
            bf16x8 aH1 = *(const bf16x8*)(baseH + aoff1 + ks);
            bf16x8 aL1 = *(const bf16x8*)(baseL + aoff1 + ks);
#pragma unroll
            for (int tile = 0; tile < 12; tile++) {
                bf16x8 wH = *(const bf16x8*)(ldsW + ((s * 2 + 0) * 12 + tile) * 512 + lane * 8);
                bf16x8 wL = *(const bf16x8*)(ldsW + ((s * 2 + 1) * 12 + tile) * 512 + lane * 8);
                acc0[tile] = __builtin_amdgcn_mfma_f32_16x16x32_bf16(aH0, wH, acc0[tile], 0, 0, 0);
                acc1[tile] = __builtin_amdgcn_mfma_f32_16x16x32_bf16(aH1, wH, acc1[tile], 0, 0, 0);
                acc0[tile] = __builtin_amdgcn_mfma_f32_16x16x32_bf16(aL0, wH, acc0[tile], 0, 0, 0);
                acc1[tile] = __builtin_amdgcn_mfma_f32_16x16x32_bf16(aL1, wH, acc1[tile], 0, 0, 0);
                acc0[tile] = __builtin_amdgcn_mfma_f32_16x16x32_bf16(aH0, wL, acc0[tile], 0, 0, 0);
                acc1[tile] = __builtin_amdgcn_mfma_f32_16x16x32_bf16(aH1, wL, acc1[tile], 0, 0, 0);
            }
        }
    }
    float scf[4], shf[4];
#pragma unroll
    for (int nt = 0; nt < 4; nt++) {
        int f = nt * 16 + r16;
        scf[nt] = aff[f]; shf[nt] = aff[64 + f];
    }
#pragma unroll
    for (int mt = 0; mt < 2; mt++) {
#pragma unroll
        for (int i = 0; i < 4; i++) {
            int node = m0 + mt * 16 + quad * 4 + i;
            if (node < N) {
                float c = cnt[node];
                float amp = c / DELTA, att = DELTA / c;
#pragma unroll
                for (int nt = 0; nt < 4; nt++) {
                    int feat = nt * 16 + r16;
                    f32x4* a = mt ? acc1 : acc0;
                    float res = fmaf(hres[(size_t)node * 64 + feat], scf[nt], shf[nt]);
                    float v = a[nt][i] + amp * a[4 + nt][i] + att * a[8 + nt][i]
                            + mb[feat] + res;
                    out[(size_t)node * 64 + feat] = v;
                }
            }
        }
    }
}

// ---------------------------------------------------------------- 64x64 GEMM (encoder / nn1 / nn2)
#define FMA16(ACC0, ACC1, ACC2, ACC3, A, W)                                \
    do {                                                                   \
        ACC0.x = fmaf(A.x, W.x, ACC0.x); ACC0.y = fmaf(A.x, W.y, ACC0.y);  \
        ACC0.z = fmaf(A.x, W.z, ACC0.z); ACC0.w = fmaf(A.x, W.w, ACC0.w);  \
        ACC1.x = fmaf(A.y, W.x, ACC1.x); ACC1.y = fmaf(A.y, W.y, ACC1.y);  \
        ACC1.z = fmaf(A.y, W.z, ACC1.z); ACC1.w = fmaf(A.y, W.w, ACC1.w);  \
        ACC2.x = fmaf(A.z, W.x, ACC2.x); ACC2.y = fmaf(A.z, W.y, ACC2.y);  \
        ACC2.z = fmaf(A.z, W.z, ACC2.z); ACC2.w = fmaf(A.z, W.w, ACC2.w);  \
        ACC3.x = fmaf(A.w, W.x, ACC3.x); ACC3.y = fmaf(A.w, W.y, ACC3.y);  \
        ACC3.z = fmaf(A.w, W.z, ACC3.z); ACC3.w = fmaf(A.w, W.w, ACC3.w);  \
    } while (0)

template <bool RELU, bool BNSTAT>
__global__ __launch_bounds__(256) void k_gemm64(const float* __restrict__ in,
                                                const float* __restrict__ W,
                                                const float* __restrict__ bias,
                                                float* __restrict__ out,
                                                float* __restrict__ bnstat, int N) {
    __shared__ float sInT[64][64];  // [k][node]
    __shared__ float sWT[64][64];   // [k][feat]
    int t = threadIdx.x;
    int tx = t & 15, ty = t >> 4;
    int n0 = blockIdx.x * 64;
    int c4 = tx * 4;
#pragma unroll
    for (int ch = 0; ch < 4; ch++) {
        int row = ch * 16 + ty;
        float4 v = make_float4(0.f, 0.f, 0.f, 0.f);
        if (n0 + row < N) v = *(const float4*)(in + (size_t)(n0 + row) * 64 + c4);
        sInT[c4 + 0][row] = v.x; sInT[c4 + 1][row] = v.y;
        sInT[c4 + 2][row] = v.z; sInT[c4 + 3][row] = v.w;
        float4 w = *(const float4*)(W + (size_t)row * 64 + c4);
        sWT[c4 + 0][row] = w.x; sWT[c4 + 1][row] = w.y;
        sWT[c4 + 2][row] = w.z; sWT[c4 + 3][row] = w.w;
    }
    __syncthreads();
    float4 acc0 = make_float4(0.f, 0.f, 0.f, 0.f);
    float4 acc1 = acc0, acc2 = acc0, acc3 = acc0;
#pragma unroll 8
    for (int k = 0; k < 64; k++) {
        float4 a = *(const float4*)(&sInT[k][ty * 4]);
        float4 w = *(const float4*)(&sWT[k][tx * 4]);
        FMA16(acc0, acc1, acc2, acc3, a, w);
    }
    float4 b4 = *(const float4*)(bias + tx * 4);
    float4 s1 = make_float4(0.f, 0.f, 0.f, 0.f);
    float4 s2 = s1;
#pragma unroll
    for (int i = 0; i < 4; i++) {
        int n = n0 + ty * 4 + i;
        if (n < N) {
            float4 v = (i == 0) ? acc0 : (i == 1) ? acc1 : (i == 2) ? acc2 : acc3;
            v.x += b4.x; v.y += b4.y; v.z += b4.z; v.w += b4.w;
            if (RELU) {
                v.x = fmaxf(v.x, 0.f); v.y = fmaxf(v.y, 0.f);
                v.z = fmaxf(v.z, 0.f); v.w = fmaxf(v.w, 0.f);
            }
            *(float4*)(out + (size_t)n * 64 + tx * 4) = v;
            if (BNSTAT) {
                s1.x += v.x; s1.y += v.y; s1.z += v.z; s1.w += v.w;
                s2.x = fmaf(v.x, v.x, s2.x); s2.y = fmaf(v.y, v.y, s2.y);
                s2.z = fmaf(v.z, v.z, s2.z); s2.w = fmaf(v.w, v.w, s2.w);
            }
        }
    }
    if (BNSTAT) {
        __syncthreads();
        float* red = &sInT[0][0];
        *(float4*)(red + ty * 64 + tx * 4) = s1;
        *(float4*)(red + 1024 + ty * 64 + tx * 4) = s2;
        __syncthreads();
        if (t < 128) {
            int d = t & 63;
            int base = (t >> 6) * 1024;
            float tot = 0.f;
#pragma unroll
            for (int r2 = 0; r2 < 16; r2++) tot += red[base + r2 * 64 + d];
            atomicAdd(&bnstat[(t >> 6) * 64 + d], tot);
        }
    }
}

// ---------------------------------------------------------------- pool (batch sorted; BN fused)
__global__ void k_pool(const float* __restrict__ h, const int* __restrict__ batch,
                       const float* __restrict__ aff, float* __restrict__ g, int N) {
    int d = threadIdx.x & 63, r = threadIdx.x >> 6;
    float sc = aff[d], sh = aff[64 + d];
    int nbase = blockIdx.x * 32;
    float acc = 0.f;
    int gcur = -1;
    for (int i = 0; i < 8; i++) {
        int n = nbase + i * 4 + r;
        if (n < N) {
            int gb = batch[n];
            if (gb != gcur) {
                if (gcur >= 0) atomicAdd(&g[gcur * 64 + d], acc);
                acc = 0.f; gcur = gb;
            }
            acc += fmaf(h[(size_t)n * 64 + d], sc, sh);
        }
    }
    if (gcur >= 0) atomicAdd(&g[gcur * 64 + d], acc);
}

// ---------------------------------------------------------------- head: relu(g@fc1)+fc2
__global__ void k_head(const float* __restrict__ g, const float* __restrict__ fc1W,
                       const float* __restrict__ fc1b, const float* __restrict__ fc2W,
                       const float* __restrict__ fc2b, float* __restrict__ out) {
    __shared__ float sg[64], sg1[64];
    int gi = blockIdx.x, t = threadIdx.x;
    sg[t] = g[gi * 64 + t];
    __syncthreads();
    float a = fc1b[t];
    for (int k = 0; k < 64; k++) a = fmaf(sg[k], fc1W[t * 64 + k], a);
    sg1[t] = fmaxf(a, 0.f);
    __syncthreads();
    if (t < 16) {
        float o = fc2b[t];
        for (int k = 0; k < 64; k++) o = fmaf(sg1[k], fc2W[t * 64 + k], o);
        out[gi * 16 + t] = o;
    }
}

// ---------------------------------------------------------------- launcher
extern "C" void kernel_launch(void* const* d_in, const int* in_sizes, int n_in,
                              void* d_out, int out_size, void* d_ws, size_t ws_size,
                              hipStream_t stream) {
    const float* x       = (const float*)d_in[0];
    const int*   eidx    = (const int*)d_in[1];
    const int*   batch   = (const int*)d_in[2];
    const float* encW    = (const float*)d_in[3];
    const float* encb    = (const float*)d_in[4];
    const float* nnW1    = (const float*)d_in[5];
    const float* nnb1    = (const float*)d_in[6];
    const float* nnW2    = (const float*)d_in[7];
    const float* nnb2    = (const float*)d_in[8];
    const float* mlpW    = (const float*)d_in[9];
    const float* mlpb    = (const float*)d_in[10];
    const float* bnG     = (const float*)d_in[11];
    const float* bnB     = (const float*)d_in[12];
    const float* fc1W    = (const float*)d_in[13];
    const float* fc1b    = (const float*)d_in[14];
    const float* fc2W    = (const float*)d_in[15];
    const float* fc2b    = (const float*)d_in[16];
    float* out = (float*)d_out;

    const int N = in_sizes[0] / 64;
    const int E = in_sizes[1] / 2;
    const int G = 512;
    const int* src = eidx;
    const int* dst = eidx + E;
    const int npp = (N + 7) / 8;  // nodes per XCD partition

    // workspace layout
    char* ws = (char*)d_ws;
    size_t off = 0;
    auto alloc = [&](size_t bytes) { size_t r = off; off = (off + bytes + 255) & ~(size_t)255; return r; };
    int*   deg     = (int*)(ws + alloc((size_t)(N + 1) * 4));
    int*   rowptr  = (int*)(ws + alloc((size_t)(N + 1) * 4));
    int*   bsums   = (int*)(ws + alloc(1024 * 4));
    int*   fill    = (int*)(ws + alloc((size_t)N * 4));
    int*   col     = (int*)(ws + alloc((size_t)E * 4));
    float* cnt     = (float*)(ws + alloc((size_t)N * 4));
    unsigned short* baseH = (unsigned short*)(ws + alloc((size_t)N * 256 * 2 + 131072));  // +pad for OOB tile reads
    unsigned short* baseL = (unsigned short*)(ws + alloc((size_t)N * 256 * 2 + 131072));
    float* hA      = (float*)(ws + alloc((size_t)N * 64 * 4));
    float* hB      = (float*)(ws + alloc((size_t)N * 64 * 4));
    float* hC      = (float*)(ws + alloc((size_t)N * 64 * 4));
    unsigned short* mWH = (unsigned short*)(ws + alloc((size_t)5 * 64 * 768 * 2));
    unsigned short* mWL = (unsigned short*)(ws + alloc((size_t)5 * 64 * 768 * 2));
    float* bnstats = (float*)(ws + alloc(5 * 128 * 4));
    float* affbuf  = (float*)(ws + alloc(6 * 128 * 4));
    float* gpool   = (float*)(ws + alloc((size_t)G * 64 * 4));

    hipMemsetAsync(deg, 0, (size_t)(N + 1) * 4, stream);
    hipMemsetAsync(fill, 0, (size_t)N * 4, stream);
    hipMemsetAsync(bnstats, 0, 5 * 128 * 4, stream);
    hipMemsetAsync(gpool, 0, (size_t)G * 64 * 4, stream);

    int total = N + 1;
    int nscan = (total + SCAN_B - 1) / SCAN_B;
    int ngrid64 = (N + 63) / 64;
    int ngrid128 = (N + 127) / 128;

    k_degree<<<1024, 256, 0, stream>>>(dst, deg, E, npp);
    k_scan_block<<<nscan, SCAN_B, 0, stream>>>(deg, rowptr, bsums, total);
    k_scan_tops<<<1, SCAN_B, 0, stream>>>(bsums, nscan);
    k_scan_add<<<nscan, SCAN_B, 0, stream>>>(rowptr, bsums, total);
    k_fill<<<1024, 256, 0, stream>>>(src, dst, rowptr, fill, col, E, npp);

    // cast all 5 layers' mlpW to bf16 hi/lo (5*64*768 = 245760 floats = 61440 float4)
    k_castw<<<240, 256, 0, stream>>>(mlpW, mWH, mWL, 61440);
    k_ident<<<1, 128, 0, stream>>>(affbuf);

    // encoder: hC = x @ encW.T + encb  (identity affine in affbuf[0])
    k_gemm64<false, false><<<ngrid64, 256, 0, stream>>>(x, encW, encb, hC, nullptr, N);

    for (int i = 0; i < 5; i++) {
        const float* aff = affbuf + i * 128;
        k_agg<<<(N + 3) / 4, 256, 0, stream>>>(hC, rowptr, col, aff, baseH, baseL, cnt, N);
        k_gemm1<<<ngrid128, 256, 0, stream>>>(baseH, baseL, cnt,
                                              mWH + (size_t)i * 64 * 768,
                                              mWL + (size_t)i * 64 * 768,
                                              mlpb + i * 64, hC, aff, hA, N);
        k_gemm64<true, false><<<ngrid64, 256, 0, stream>>>(hA, nnW1 + (size_t)i * 4096,
                                                           nnb1 + i * 64, hB, nullptr, N);
        k_gemm64<true, true><<<ngrid64, 256, 0, stream>>>(hB, nnW2 + (size_t)i * 4096,
                                                          nnb2 + i * 64, hC, bnstats + i * 128, N);
        k_bnfin<<<1, 64, 0, stream>>>(bnstats + i * 128, bnG + i * 64, bnB + i * 64,
                                      affbuf + (i + 1) * 128, 1.f / (float)N);
    }

    k_pool<<<(N + 31) / 32, 256, 0, stream>>>(hC, batch, affbuf + 5 * 128, gpool, N);
    k_head<<<G, 64, 0, stream>>>(gpool, fc1W, fc1b, fc2W, fc2b, out);
}

// Round 8
// 1164.177 us; speedup vs baseline: 11.3838x; 1.1498x over previous
//
#include <hip/hip_runtime.h>
#include <hip/hip_bf16.h>

#define DELTA 2.5749f
#define BN_EPS 1e-5f

typedef __attribute__((ext_vector_type(8))) _Float16 f16x8;
typedef __attribute__((ext_vector_type(4))) float f32x4;

__device__ inline unsigned short f2h(float f) {
    union { _Float16 h; unsigned short u; } v;
    v.h = (_Float16)f;  // RNE
    return v.u;
}

// ---------------------------------------------------------------- CSR build (XCD-partitioned)
__global__ __launch_bounds__(256) void k_degree(const int* __restrict__ dst,
                                                int* __restrict__ deg, int E, int npp) {
    int part = blockIdx.x & 7;
    int lo = part * npp, hi = lo + npp;
    int stride = (gridDim.x >> 3) * 256;
    for (int e = (blockIdx.x >> 3) * 256 + threadIdx.x; e < E; e += stride) {
        int d = dst[e];
        if (d >= lo && d < hi) atomicAdd(&deg[d], 1);
    }
}

#define SCAN_B 1024
__global__ void k_scan_block(const int* __restrict__ deg, int* __restrict__ excl,
                             int* __restrict__ bsums, int total) {
    __shared__ int s[SCAN_B];
    int t = threadIdx.x, i = blockIdx.x * SCAN_B + t;
    int v = (i < total) ? deg[i] : 0;
    s[t] = v; __syncthreads();
    for (int off = 1; off < SCAN_B; off <<= 1) {
        int x = (t >= off) ? s[t - off] : 0;
        __syncthreads();
        s[t] += x;
        __syncthreads();
    }
    if (i < total) excl[i] = s[t] - v;
    if (t == SCAN_B - 1) bsums[blockIdx.x] = s[t];
}

__global__ void k_scan_tops(int* __restrict__ bsums, int nb) {
    __shared__ int s[SCAN_B];
    int t = threadIdx.x;
    int v = (t < nb) ? bsums[t] : 0;
    s[t] = v; __syncthreads();
    for (int off = 1; off < SCAN_B; off <<= 1) {
        int x = (t >= off) ? s[t - off] : 0;
        __syncthreads();
        s[t] += x;
        __syncthreads();
    }
    if (t < nb) bsums[t] = s[t] - v;  // exclusive
}

__global__ void k_scan_add(int* __restrict__ excl, const int* __restrict__ bsums, int total) {
    int i = blockIdx.x * SCAN_B + threadIdx.x;
    if (i < total) excl[i] += bsums[blockIdx.x];
}

__global__ __launch_bounds__(256) void k_fill(const int* __restrict__ src,
                                              const int* __restrict__ dst,
                                              const int* __restrict__ rowptr,
                                              int* __restrict__ fill,
                                              int* __restrict__ col, int E, int npp) {
    int part = blockIdx.x & 7;
    int lo = part * npp, hi = lo + npp;
    int stride = (gridDim.x >> 3) * 256;
    for (int e = (blockIdx.x >> 3) * 256 + threadIdx.x; e < E; e += stride) {
        int d = dst[e];
        if (d >= lo && d < hi) {
            int pos = rowptr[d] + atomicAdd(&fill[d], 1);
            col[pos] = src[e];
        }
    }
}

// ---------------------------------------------------------------- weight cast f32 -> f16
__global__ void k_castw(const float* __restrict__ w, unsigned short* __restrict__ o, int n4) {
    int i = blockIdx.x * 256 + threadIdx.x;
    if (i < n4) {
        float4 v = ((const float4*)w)[i];
        ushort4 r;
        r.x = f2h(v.x); r.y = f2h(v.y); r.z = f2h(v.z); r.w = f2h(v.w);
        ((ushort4*)o)[i] = r;
    }
}

// ---------------------------------------------------------------- BN affine helpers
__global__ void k_ident(float* __restrict__ aff) {
    int t = threadIdx.x;  // 128
    aff[t] = (t < 64) ? 1.f : 0.f;
}

__global__ void k_bnfin(const float* __restrict__ stat, const float* __restrict__ gamma,
                        const float* __restrict__ beta, float* __restrict__ aff, float invN) {
    int d = threadIdx.x;  // 64
    float mu = stat[d] * invN;
    float var = stat[64 + d] * invN - mu * mu;
    float sc = rsqrtf(var + BN_EPS) * gamma[d];
    aff[d] = sc;
    aff[64 + d] = beta[d] - mu * sc;
}

// ---------------------------------------------------------------- aggregation (BN fused, f16 out)
#define AGG_ACC(V)                                                         \
    do {                                                                   \
        V.x = fmaf(V.x, sc4.x, sh4.x); V.y = fmaf(V.y, sc4.y, sh4.y);      \
        V.z = fmaf(V.z, sc4.z, sh4.z); V.w = fmaf(V.w, sc4.w, sh4.w);      \
        sum.x += V.x; sum.y += V.y; sum.z += V.z; sum.w += V.w;            \
        sq.x = fmaf(V.x, V.x, sq.x); sq.y = fmaf(V.y, V.y, sq.y);          \
        sq.z = fmaf(V.z, V.z, sq.z); sq.w = fmaf(V.w, V.w, sq.w);          \
        mx.x = fmaxf(mx.x, V.x); mx.y = fmaxf(mx.y, V.y);                  \
        mx.z = fmaxf(mx.z, V.z); mx.w = fmaxf(mx.w, V.w);                  \
    } while (0)

__global__ __launch_bounds__(256) void k_agg(const float* __restrict__ h,
                                             const int* __restrict__ rowptr,
                                             const int* __restrict__ col,
                                             const float* __restrict__ aff,
                                             unsigned short* __restrict__ baseF,
                                             float* __restrict__ cnt, int N) {
    int node = blockIdx.x * 4 + (threadIdx.x >> 6);
    int lane = threadIdx.x & 63;
    if (node >= N) return;
    int slot = lane >> 4;        // which of 4 concurrent edges
    int fo = (lane & 15) * 4;    // feature offset
    float4 sc4 = *(const float4*)(aff + fo);
    float4 sh4 = *(const float4*)(aff + 64 + fo);
    int s0 = rowptr[node], s1 = rowptr[node + 1];
    int deg = s1 - s0;
    float4 sum = make_float4(0.f, 0.f, 0.f, 0.f);
    float4 sq = sum;
    float4 mx = make_float4(-INFINITY, -INFINITY, -INFINITY, -INFINITY);
    int e = s0 + slot;
    for (; e + 12 < s1; e += 16) {
        int sA = col[e], sB = col[e + 4], sC = col[e + 8], sD = col[e + 12];
        float4 v1 = *(const float4*)(h + (size_t)sA * 64 + fo);
        float4 v2 = *(const float4*)(h + (size_t)sB * 64 + fo);
        float4 v3 = *(const float4*)(h + (size_t)sC * 64 + fo);
        float4 v4 = *(const float4*)(h + (size_t)sD * 64 + fo);
        AGG_ACC(v1); AGG_ACC(v2); AGG_ACC(v3); AGG_ACC(v4);
    }
    for (; e < s1; e += 4) {
        int s = col[e];
        float4 v = *(const float4*)(h + (size_t)s * 64 + fo);
        AGG_ACC(v);
    }
#pragma unroll
    for (int m = 16; m <= 32; m <<= 1) {
        sum.x += __shfl_xor(sum.x, m); sum.y += __shfl_xor(sum.y, m);
        sum.z += __shfl_xor(sum.z, m); sum.w += __shfl_xor(sum.w, m);
        sq.x += __shfl_xor(sq.x, m); sq.y += __shfl_xor(sq.y, m);
        sq.z += __shfl_xor(sq.z, m); sq.w += __shfl_xor(sq.w, m);
        mx.x = fmaxf(mx.x, __shfl_xor(mx.x, m)); mx.y = fmaxf(mx.y, __shfl_xor(mx.y, m));
        mx.z = fmaxf(mx.z, __shfl_xor(mx.z, m)); mx.w = fmaxf(mx.w, __shfl_xor(mx.w, m));
    }
    float c = (float)(deg > 0 ? deg : 1);
    float ic = 1.f / c;
    float4 mean = make_float4(sum.x * ic, sum.y * ic, sum.z * ic, sum.w * ic);
    float4 var = make_float4(fmaxf(fmaf(-mean.x, mean.x, sq.x * ic), 0.f),
                             fmaxf(fmaf(-mean.y, mean.y, sq.y * ic), 0.f),
                             fmaxf(fmaf(-mean.z, mean.z, sq.z * ic), 0.f),
                             fmaxf(fmaf(-mean.w, mean.w, sq.w * ic), 0.f));
    if (deg == 0) mx = make_float4(0.f, 0.f, 0.f, 0.f);
    float4 wv = (slot == 0) ? sum : (slot == 1) ? mx : (slot == 2) ? mean : var;
    ushort4 of;
    of.x = f2h(wv.x); of.y = f2h(wv.y); of.z = f2h(wv.z); of.w = f2h(wv.w);
    *(ushort4*)(baseF + (size_t)node * 256 + slot * 64 + fo) = of;
    if (lane == 0) cnt[node] = c;
}

// ---------------------------------------------------------------- big GEMM via MFMA f16 (single-plane)
// Weights staged per 64-k chunk into LDS in fragment order (24 records x 1KB = 24KB).
// A registers prefetched one chunk ahead; residual applies BN affine on the fly.
__global__ __launch_bounds__(256) void k_gemm1(const unsigned short* __restrict__ baseF,
                                               const float* __restrict__ cnt,
                                               const unsigned short* __restrict__ mWF,
                                               const float* __restrict__ mb,
                                               const float* __restrict__ hres,
                                               const float* __restrict__ aff,
                                               float* __restrict__ out, int N) {
    __shared__ _Float16 ldsW[24 * 512];  // rec = s*12 + mat*4 + nt
    int t = threadIdx.x;
    int wave = t >> 6, lane = t & 63;
    int r16 = lane & 15, quad = lane >> 4;
    int m0 = blockIdx.x * 128 + wave * 32;   // first m-tile; second is m0+16
    const _Float16* aptr0 = (const _Float16*)baseF + (size_t)(m0 + r16) * 256 + quad * 8;
    const _Float16* aptr1 = (const _Float16*)baseF + (size_t)(m0 + 16 + r16) * 256 + quad * 8;

    f32x4 acc0[12], acc1[12];
#pragma unroll
    for (int i = 0; i < 12; i++) {
        acc0[i] = (f32x4){0.f, 0.f, 0.f, 0.f};
        acc1[i] = (f32x4){0.f, 0.f, 0.f, 0.f};
    }
    // A fragments for chunk 0: [s][m-tile]
    f16x8 a00 = *(const f16x8*)(aptr0 + 0);
    f16x8 a01 = *(const f16x8*)(aptr1 + 0);
    f16x8 a10 = *(const f16x8*)(aptr0 + 32);
    f16x8 a11 = *(const f16x8*)(aptr1 + 32);

#pragma unroll 1
    for (int chunk = 0; chunk < 4; chunk++) {
        if (chunk) __syncthreads();
        // stage this chunk's weights (24 records / 4 waves = 6 per thread)
#pragma unroll
        for (int rb = 0; rb < 24; rb += 4) {
            int rec = rb + wave;
            int s = rec / 12, tile = rec % 12;
            int mat = tile >> 2, nt = tile & 3;
            uint4 v = *(const uint4*)(mWF + (size_t)(nt * 16 + r16) * 768 + mat * 256
                                      + chunk * 64 + s * 32 + quad * 8);
            *(uint4*)((unsigned short*)ldsW + rec * 512 + lane * 8) = v;
        }
        __syncthreads();
        // prefetch next chunk's A (latency hides under this chunk's compute)
        f16x8 n00, n01, n10, n11;
        if (chunk < 3) {
            int ko = (chunk + 1) * 64;
            n00 = *(const f16x8*)(aptr0 + ko);
            n01 = *(const f16x8*)(aptr1 + ko);
            n10 = *(const f16x8*)(aptr0 + ko + 32);
            n11 = *(const f16x8*)(aptr1 + ko + 32);
        }
#pragma unroll
        for (int s = 0; s < 2; s++) {
            f16x8 af0 = s ? a10 : a00;
            f16x8 af1 = s ? a11 : a01;
#pragma unroll
            for (int tile = 0; tile < 12; tile++) {
                f16x8 wF = *(const f16x8*)(ldsW + (s * 12 + tile) * 512 + lane * 8);
                acc0[tile] = __builtin_amdgcn_mfma_f32_16x16x32_f16(af0, wF, acc0[tile], 0, 0, 0);
                acc1[tile] = __builtin_amdgcn_mfma_f32_16x16x32_f16(af1, wF, acc1[tile], 0, 0, 0);
            }
        }
        a00 = n00; a01 = n01; a10 = n10; a11 = n11;
    }
    float scf[4], shf[4];
#pragma unroll
    for (int nt = 0; nt < 4; nt++) {
        int f = nt * 16 + r16;
        scf[nt] = aff[f]; shf[nt] = aff[64 + f];
    }
#pragma unroll
    for (int mt = 0; mt < 2; mt++) {
#pragma unroll
        for (int i = 0; i < 4; i++) {
            int node = m0 + mt * 16 + quad * 4 + i;
            if (node < N) {
                float c = cnt[node];
                float amp = c / DELTA, att = DELTA / c;
#pragma unroll
                for (int nt = 0; nt < 4; nt++) {
                    int feat = nt * 16 + r16;
                    f32x4* a = mt ? acc1 : acc0;
                    float res = fmaf(hres[(size_t)node * 64 + feat], scf[nt], shf[nt]);
                    float v = a[nt][i] + amp * a[4 + nt][i] + att * a[8 + nt][i]
                            + mb[feat] + res;
                    out[(size_t)node * 64 + feat] = v;
                }
            }
        }
    }
}

// ---------------------------------------------------------------- 64x64 GEMM (encoder / nn1 / nn2)
#define FMA16(ACC0, ACC1, ACC2, ACC3, A, W)                                \
    do {                                                                   \
        ACC0.x = fmaf(A.x, W.x, ACC0.x); ACC0.y = fmaf(A.x, W.y, ACC0.y);  \
        ACC0.z = fmaf(A.x, W.z, ACC0.z); ACC0.w = fmaf(A.x, W.w, ACC0.w);  \
        ACC1.x = fmaf(A.y, W.x, ACC1.x); ACC1.y = fmaf(A.y, W.y, ACC1.y);  \
        ACC1.z = fmaf(A.y, W.z, ACC1.z); ACC1.w = fmaf(A.y, W.w, ACC1.w);  \
        ACC2.x = fmaf(A.z, W.x, ACC2.x); ACC2.y = fmaf(A.z, W.y, ACC2.y);  \
        ACC2.z = fmaf(A.z, W.z, ACC2.z); ACC2.w = fmaf(A.z, W.w, ACC2.w);  \
        ACC3.x = fmaf(A.w, W.x, ACC3.x); ACC3.y = fmaf(A.w, W.y, ACC3.y);  \
        ACC3.z = fmaf(A.w, W.z, ACC3.z); ACC3.w = fmaf(A.w, W.w, ACC3.w);  \
    } while (0)

template <bool RELU, bool BNSTAT>
__global__ __launch_bounds__(256) void k_gemm64(const float* __restrict__ in,
                                                const float* __restrict__ W,
                                                const float* __restrict__ bias,
                                                float* __restrict__ out,
                                                float* __restrict__ bnstat, int N) {
    __shared__ float sInT[64][64];  // [k][node]
    __shared__ float sWT[64][64];   // [k][feat]
    int t = threadIdx.x;
    int tx = t & 15, ty = t >> 4;
    int n0 = blockIdx.x * 64;
    int c4 = tx * 4;
#pragma unroll
    for (int ch = 0; ch < 4; ch++) {
        int row = ch * 16 + ty;
        float4 v = make_float4(0.f, 0.f, 0.f, 0.f);
        if (n0 + row < N) v = *(const float4*)(in + (size_t)(n0 + row) * 64 + c4);
        sInT[c4 + 0][row] = v.x; sInT[c4 + 1][row] = v.y;
        sInT[c4 + 2][row] = v.z; sInT[c4 + 3][row] = v.w;
        float4 w = *(const float4*)(W + (size_t)row * 64 + c4);
        sWT[c4 + 0][row] = w.x; sWT[c4 + 1][row] = w.y;
        sWT[c4 + 2][row] = w.z; sWT[c4 + 3][row] = w.w;
    }
    __syncthreads();
    float4 acc0 = make_float4(0.f, 0.f, 0.f, 0.f);
    float4 acc1 = acc0, acc2 = acc0, acc3 = acc0;
#pragma unroll 8
    for (int k = 0; k < 64; k++) {
        float4 a = *(const float4*)(&sInT[k][ty * 4]);
        float4 w = *(const float4*)(&sWT[k][tx * 4]);
        FMA16(acc0, acc1, acc2, acc3, a, w);
    }
    float4 b4 = *(const float4*)(bias + tx * 4);
    float4 s1 = make_float4(0.f, 0.f, 0.f, 0.f);
    float4 s2 = s1;
#pragma unroll
    for (int i = 0; i < 4; i++) {
        int n = n0 + ty * 4 + i;
        if (n < N) {
            float4 v = (i == 0) ? acc0 : (i == 1) ? acc1 : (i == 2) ? acc2 : acc3;
            v.x += b4.x; v.y += b4.y; v.z += b4.z; v.w += b4.w;
            if (RELU) {
                v.x = fmaxf(v.x, 0.f); v.y = fmaxf(v.y, 0.f);
                v.z = fmaxf(v.z, 0.f); v.w = fmaxf(v.w, 0.f);
            }
            *(float4*)(out + (size_t)n * 64 + tx * 4) = v;
            if (BNSTAT) {
                s1.x += v.x; s1.y += v.y; s1.z += v.z; s1.w += v.w;
                s2.x = fmaf(v.x, v.x, s2.x); s2.y = fmaf(v.y, v.y, s2.y);
                s2.z = fmaf(v.z, v.z, s2.z); s2.w = fmaf(v.w, v.w, s2.w);
            }
        }
    }
    if (BNSTAT) {
        __syncthreads();
        float* red = &sInT[0][0];
        *(float4*)(red + ty * 64 + tx * 4) = s1;
        *(float4*)(red + 1024 + ty * 64 + tx * 4) = s2;
        __syncthreads();
        if (t < 128) {
            int d = t & 63;
            int base = (t >> 6) * 1024;
            float tot = 0.f;
#pragma unroll
            for (int r2 = 0; r2 < 16; r2++) tot += red[base + r2 * 64 + d];
            atomicAdd(&bnstat[(t >> 6) * 64 + d], tot);
        }
    }
}

// ---------------------------------------------------------------- pool (batch sorted; BN fused)
__global__ void k_pool(const float* __restrict__ h, const int* __restrict__ batch,
                       const float* __restrict__ aff, float* __restrict__ g, int N) {
    int d = threadIdx.x & 63, r = threadIdx.x >> 6;
    float sc = aff[d], sh = aff[64 + d];
    int nbase = blockIdx.x * 32;
    float acc = 0.f;
    int gcur = -1;
    for (int i = 0; i < 8; i++) {
        int n = nbase + i * 4 + r;
        if (n < N) {
            int gb = batch[n];
            if (gb != gcur) {
                if (gcur >= 0) atomicAdd(&g[gcur * 64 + d], acc);
                acc = 0.f; gcur = gb;
            }
            acc += fmaf(h[(size_t)n * 64 + d], sc, sh);
        }
    }
    if (gcur >= 0) atomicAdd(&g[gcur * 64 + d], acc);
}

// ---------------------------------------------------------------- head: relu(g@fc1)+fc2
__global__ void k_head(const float* __restrict__ g, const float* __restrict__ fc1W,
                       const float* __restrict__ fc1b, const float* __restrict__ fc2W,
                       const float* __restrict__ fc2b, float* __restrict__ out) {
    __shared__ float sg[64], sg1[64];
    int gi = blockIdx.x, t = threadIdx.x;
    sg[t] = g[gi * 64 + t];
    __syncthreads();
    float a = fc1b[t];
    for (int k = 0; k < 64; k++) a = fmaf(sg[k], fc1W[t * 64 + k], a);
    sg1[t] = fmaxf(a, 0.f);
    __syncthreads();
    if (t < 16) {
        float o = fc2b[t];
        for (int k = 0; k < 64; k++) o = fmaf(sg1[k], fc2W[t * 64 + k], o);
        out[gi * 16 + t] = o;
    }
}

// ---------------------------------------------------------------- launcher
extern "C" void kernel_launch(void* const* d_in, const int* in_sizes, int n_in,
                              void* d_out, int out_size, void* d_ws, size_t ws_size,
                              hipStream_t stream) {
    const float* x       = (const float*)d_in[0];
    const int*   eidx    = (const int*)d_in[1];
    const int*   batch   = (const int*)d_in[2];
    const float* encW    = (const float*)d_in[3];
    const float* encb    = (const float*)d_in[4];
    const float* nnW1    = (const float*)d_in[5];
    const float* nnb1    = (const float*)d_in[6];
    const float* nnW2    = (const float*)d_in[7];
    const float* nnb2    = (const float*)d_in[8];
    const float* mlpW    = (const float*)d_in[9];
    const float* mlpb    = (const float*)d_in[10];
    const float* bnG     = (const float*)d_in[11];
    const float* bnB     = (const float*)d_in[12];
    const float* fc1W    = (const float*)d_in[13];
    const float* fc1b    = (const float*)d_in[14];
    const float* fc2W    = (const float*)d_in[15];
    const float* fc2b    = (const float*)d_in[16];
    float* out = (float*)d_out;

    const int N = in_sizes[0] / 64;
    const int E = in_sizes[1] / 2;
    const int G = 512;
    const int* src = eidx;
    const int* dst = eidx + E;
    const int npp = (N + 7) / 8;  // nodes per XCD partition

    // workspace layout
    char* ws = (char*)d_ws;
    size_t off = 0;
    auto alloc = [&](size_t bytes) { size_t r = off; off = (off + bytes + 255) & ~(size_t)255; return r; };
    int*   deg     = (int*)(ws + alloc((size_t)(N + 1) * 4));
    int*   rowptr  = (int*)(ws + alloc((size_t)(N + 1) * 4));
    int*   bsums   = (int*)(ws + alloc(1024 * 4));
    int*   fill    = (int*)(ws + alloc((size_t)N * 4));
    int*   col     = (int*)(ws + alloc((size_t)E * 4));
    float* cnt     = (float*)(ws + alloc((size_t)N * 4));
    unsigned short* baseF = (unsigned short*)(ws + alloc((size_t)N * 256 * 2 + 131072));  // +pad for OOB tile reads
    float* hA      = (float*)(ws + alloc((size_t)N * 64 * 4));
    float* hB      = (float*)(ws + alloc((size_t)N * 64 * 4));
    float* hC      = (float*)(ws + alloc((size_t)N * 64 * 4));
    unsigned short* mWF = (unsigned short*)(ws + alloc((size_t)5 * 64 * 768 * 2));
    float* bnstats = (float*)(ws + alloc(5 * 128 * 4));
    float* affbuf  = (float*)(ws + alloc(6 * 128 * 4));
    float* gpool   = (float*)(ws + alloc((size_t)G * 64 * 4));

    hipMemsetAsync(deg, 0, (size_t)(N + 1) * 4, stream);
    hipMemsetAsync(fill, 0, (size_t)N * 4, stream);
    hipMemsetAsync(bnstats, 0, 5 * 128 * 4, stream);
    hipMemsetAsync(gpool, 0, (size_t)G * 64 * 4, stream);

    int total = N + 1;
    int nscan = (total + SCAN_B - 1) / SCAN_B;
    int ngrid64 = (N + 63) / 64;
    int ngrid128 = (N + 127) / 128;

    k_degree<<<1024, 256, 0, stream>>>(dst, deg, E, npp);
    k_scan_block<<<nscan, SCAN_B, 0, stream>>>(deg, rowptr, bsums, total);
    k_scan_tops<<<1, SCAN_B, 0, stream>>>(bsums, nscan);
    k_scan_add<<<nscan, SCAN_B, 0, stream>>>(rowptr, bsums, total);
    k_fill<<<1024, 256, 0, stream>>>(src, dst, rowptr, fill, col, E, npp);

    // cast all 5 layers' mlpW to f16 (5*64*768 = 245760 floats = 61440 float4)
    k_castw<<<240, 256, 0, stream>>>(mlpW, mWF, 61440);
    k_ident<<<1, 128, 0, stream>>>(affbuf);

    // encoder: hC = x @ encW.T + encb  (identity affine in affbuf[0])
    k_gemm64<false, false><<<ngrid64, 256, 0, stream>>>(x, encW, encb, hC, nullptr, N);

    for (int i = 0; i < 5; i++) {
        const float* aff = affbuf + i * 128;
        k_agg<<<(N + 3) / 4, 256, 0, stream>>>(hC, rowptr, col, aff, baseF, cnt, N);
        k_gemm1<<<ngrid128, 256, 0, stream>>>(baseF, cnt,
                                              mWF + (size_t)i * 64 * 768,
                                              mlpb + i * 64, hC, aff, hA, N);
        k_gemm64<true, false><<<ngrid64, 256, 0, stream>>>(hA, nnW1 + (size_t)i * 4096,
                                                           nnb1 + i * 64, hB, nullptr, N);
        k_gemm64<true, true><<<ngrid64, 256, 0, stream>>>(hB, nnW2 + (size_t)i * 4096,
                                                          nnb2 + i * 64, hC, bnstats + i * 128, N);
        k_bnfin<<<1, 64, 0, stream>>>(bnstats + i * 128, bnG + i * 64, bnB + i * 64,
                                      affbuf + (i + 1) * 128, 1.f / (float)N);
    }

    k_pool<<<(N + 31) / 32, 256, 0, stream>>>(hC, batch, affbuf + 5 * 128, gpool, N);
    k_head<<<G, 64, 0, stream>>>(gpool, fc1W, fc1b, fc2W, fc2b, out);
}